// Round 13
// baseline (553.838 us; speedup 1.0000x reference)
//
#include <hip/hip_runtime.h>
#include <cstdint>
#include <cstddef>

typedef __bf16 bf16;
typedef __bf16 bf16x8 __attribute__((ext_vector_type(8)));
typedef __bf16 bf16x4 __attribute__((ext_vector_type(4)));
typedef float  f32x4  __attribute__((ext_vector_type(4)));

#define B_   32
#define S_   384
#define D_   512
#define H_   8
#define DH_  64
#define DFF_ 2048
#define NTOK (B_*S_)

__device__ __forceinline__ void gload16(const void* g, void* l){
  __builtin_amdgcn_global_load_lds((__attribute__((address_space(1))) uint32_t*)(g),
                                   (__attribute__((address_space(3))) uint32_t*)(l), 16, 0, 0);
}

// ---------------- fused prep: 10 weight transposes (fp32 [K,N] -> bf16 [N,K]) + bn_prep ----------------
struct PrepArgs { const float* w8[8]; const float* wff1; const float* wff2; const float* bn[16]; };
__global__ __launch_bounds__(256) void prep_all(PrepArgs pa, bf16* Wt8, bf16* Wff1t, bf16* Wff2t,
                                                float* sc, float* sh){
  __shared__ float t[64][65];
  int id = blockIdx.x;
  if (id < 1024){
    const float* src; bf16* dst; int R, C, tr, tc;
    if (id < 512){
      int w = id >> 6, tl = id & 63;
      src = pa.w8[w]; dst = Wt8 + (size_t)w*262144; R = 512; C = 512;
      tr = (tl>>3)*64; tc = (tl&7)*64;
    } else if (id < 768){
      int tl = id - 512;                       // Wff1 [512,2048] -> [2048,512]
      src = pa.wff1; dst = Wff1t; R = 512; C = 2048;
      tr = (tl>>5)*64; tc = (tl&31)*64;
    } else {
      int tl = id - 768;                       // Wff2 [2048,512] -> [512,2048]
      src = pa.wff2; dst = Wff2t; R = 2048; C = 512;
      tr = (tl>>3)*64; tc = (tl&7)*64;
    }
    for (int i=threadIdx.x; i<4096; i+=256){ int r=i>>6, c=i&63; t[r][c] = src[(size_t)(tr+r)*C + tc+c]; }
    __syncthreads();
    for (int i=threadIdx.x; i<4096; i+=256){ int c=i>>6, r=i&63; dst[(size_t)(tc+c)*R + tr+r] = (bf16)t[r][c]; }
  } else {
    int t2 = id - 1024;                        // 8 blocks: 4 bns x 2 halves
    int i = t2 >> 1, half = t2 & 1;
    int n = half*256 + threadIdx.x;
    float g = pa.bn[i*4+0][n], b = pa.bn[i*4+1][n], m = pa.bn[i*4+2][n], v = pa.bn[i*4+3][n];
    float s = g * rsqrtf(v + 1e-3f);
    sc[i*512+n] = s; sh[i*512+n] = b - m*s;
  }
}

// fused: y=0 -> bn2(enc) -> E2 ; y=1 -> bf16(x2) -> X2b
__global__ __launch_bounds__(256) void cvt2(const float* __restrict__ enc, const float* __restrict__ x2,
                                            const float* __restrict__ sc, const float* __restrict__ sh,
                                            bf16* __restrict__ E2, bf16* __restrict__ X2b){
  size_t e0 = ((size_t)blockIdx.x*256 + threadIdx.x)*4;
  if (blockIdx.y == 0){
    int n0 = (int)(e0 & (D_-1));
    f32x4 xv = *(const f32x4*)(enc + e0);
    bf16x4 ov;
    #pragma unroll
    for (int j=0;j<4;j++) ov[j] = (bf16)(xv[j]*sc[n0+j] + sh[n0+j]);
    *(bf16x4*)(E2 + e0) = ov;
  } else {
    f32x4 xv = *(const f32x4*)(x2 + e0);
    bf16x4 ov;
    #pragma unroll
    for (int j=0;j<4;j++) ov[j] = (bf16)xv[j];
    *(bf16x4*)(X2b + e0) = ov;
  }
}

// ---------------- 64x128 GEMM (N=512 shapes: o1,o2,ff2), BK=64, 2-phase dbuf, XOR swizzle ------------
__global__ __launch_bounds__(256,3) void gemm_bt(
    const bf16* __restrict__ A, const bf16* __restrict__ Wt,
    const float* __restrict__ b0,
    const bf16* __restrict__ residb,
    const float* __restrict__ bsc, const float* __restrict__ bsh,
    bf16* __restrict__ o0,
    float* __restrict__ of, bf16* __restrict__ pre,
    int M, int N, int K, int relu)
{
  __shared__ bf16 As[2][64*64];
  __shared__ bf16 Bs[2][128*64];
  int nwg = gridDim.x;
  int cpx = nwg >> 3;
  int bid = blockIdx.x;
  int swz = (bid & 7)*cpx + (bid >> 3);
  int tiles_n = N >> 7;
  int tm = swz / tiles_n, tn = swz - tm*tiles_n;

  int tid = threadIdx.x, wave = tid>>6, lane = tid&63;
  int lhi = lane>>4, llo = lane&15;
  int lrow = lane>>3, lcol = lane&7;
  int wr = wave>>1, wc = wave&1;

  f32x4 acc[2][4];
  #pragma unroll
  for (int i=0;i<2;i++)
    #pragma unroll
    for (int j=0;j<4;j++) acc[i][j] = (f32x4){0.f,0.f,0.f,0.f};

  const bf16* Abase = A  + (size_t)(tm*64)  * K;
  const bf16* Bbase = Wt + (size_t)(tn*128) * K;

  int arow0 = wave*16, brow0 = wave*32;

  auto STAGE = [&](int buf, int kt){
    #pragma unroll
    for (int q=0;q<2;q++){
      int r = arow0 + q*8 + lrow;
      int s = lcol ^ (r&7);
      gload16(Abase + (size_t)r*K + kt + s*8, (char*)&As[buf][0] + wave*2048 + q*1024);
    }
    #pragma unroll
    for (int q=0;q<4;q++){
      int r = brow0 + q*8 + lrow;
      int s = lcol ^ (r&7);
      gload16(Bbase + (size_t)r*K + kt + s*8, (char*)&Bs[buf][0] + wave*4096 + q*1024);
    }
  };

  STAGE(0, 0);
  __syncthreads();
  int nt = K >> 6;
  int cur = 0;
  for (int t=0; t<nt; ++t){
    if (t+1 < nt) STAGE(cur^1, (t+1)<<6);
    #pragma unroll
    for (int ks=0; ks<2; ks++){
      bf16x8 af[2], bfr[4];
      #pragma unroll
      for (int i=0;i<2;i++){
        int row = wr*32 + i*16 + llo;
        int slot = (ks*4 + lhi) ^ (row&7);
        af[i] = *(const bf16x8*)&As[cur][row*64 + slot*8];
      }
      #pragma unroll
      for (int j=0;j<4;j++){
        int row = wc*64 + j*16 + llo;
        int slot = (ks*4 + lhi) ^ (row&7);
        bfr[j] = *(const bf16x8*)&Bs[cur][row*64 + slot*8];
      }
      #pragma unroll
      for (int i=0;i<2;i++)
        #pragma unroll
        for (int j=0;j<4;j++)
          acc[i][j] = __builtin_amdgcn_mfma_f32_16x16x32_bf16(af[i], bfr[j], acc[i][j], 0,0,0);
    }
    __syncthreads();
    cur ^= 1;
  }

  int m0 = tm*64 + wr*32, n0 = tn*128 + wc*64;
  #pragma unroll
  for (int i=0;i<2;i++){
    #pragma unroll
    for (int j=0;j<4;j++){
      int gn = n0 + j*16 + llo;
      #pragma unroll
      for (int rr=0;rr<4;rr++){
        int gm = m0 + i*16 + lhi*4 + rr;
        float v = acc[i][j][rr];
        if (b0) v += b0[gn & 511];
        if (residb) v += (float)residb[(size_t)gm*N + gn];
        if (pre)  pre[(size_t)gm*N + gn] = (bf16)v;
        if (bsc)  v = v*bsc[gn & 511] + bsh[gn & 511];
        if (relu) v = fmaxf(v, 0.f);
        if (of) of[(size_t)gm*N + gn] = v;
        else    o0[(size_t)gm*N + gn] = (bf16)v;
      }
    }
  }
}

// ---------------- 256x128 GEMM (big shapes: QKV, q2kv2, ff1), BK=32, 8 waves, 2-phase dbuf ------
// Same per-wave 64x64 geometry as before (acc[4][4], 16 MFMA/step) but 4x2 wave grid ->
// 2x output per block through the same 16-step latency chain. LDS 48 KB -> 3 blocks/CU.
// 64 B rows -> swizzle (r>>1)&3 (conflicts measured 0). A-select: tiles tn >= tnA read A2.
__global__ __launch_bounds__(512,6) void gemm_bt2(
    const bf16* __restrict__ A, const bf16* __restrict__ A2, int tnA,
    const bf16* __restrict__ Wt,
    const float* __restrict__ b0, const float* __restrict__ b1, const float* __restrict__ b2,
    bf16* __restrict__ o0, bf16* __restrict__ o1b,
    bf16* __restrict__ vt, int vseg,
    int M, int N, int K, int relu, int mode)
{
  __shared__ bf16 As[2][256*32];   // 16 KB each
  __shared__ bf16 Bs[2][128*32];   // 8 KB each
  int nwg = gridDim.x;
  int cpx = nwg >> 3;
  int bid = blockIdx.x;
  int swz = (bid & 7)*cpx + (bid >> 3);
  int tiles_n = N >> 7;
  int tm = swz / tiles_n, tn = swz - tm*tiles_n;

  int tid = threadIdx.x, wave = tid>>6, lane = tid&63;
  int lhi = lane>>4, llo = lane&15;
  int srow = tid>>2, sslot = tid&3;      // staging: 128 rows/pass over 512 threads
  int wr = wave>>1, wc = wave&1;         // 4x2 wave grid

  f32x4 acc[4][4];
  #pragma unroll
  for (int i=0;i<4;i++)
    #pragma unroll
    for (int j=0;j<4;j++) acc[i][j] = (f32x4){0.f,0.f,0.f,0.f};

  const bf16* Asrc = (A2 && tn >= tnA) ? A2 : A;
  const bf16* Abase = Asrc + (size_t)(tm*256) * K;
  const bf16* Bbase = Wt   + (size_t)(tn*128) * K;

  auto STAGE = [&](int buf, int kt){
    #pragma unroll
    for (int q=0;q<2;q++){                     // A: 256 rows = 2 passes of 128
      int r = q*128 + srow;
      int s = sslot ^ ((r>>1)&3);
      gload16(Abase + (size_t)r*K + kt + s*8, (char*)&As[buf][0] + q*8192 + wave*1024);
    }
    {                                           // B: 128 rows = 1 pass
      int r = srow;
      int s = sslot ^ ((r>>1)&3);
      gload16(Bbase + (size_t)r*K + kt + s*8, (char*)&Bs[buf][0] + wave*1024);
    }
  };

  STAGE(0, 0);
  __syncthreads();
  int nt = K >> 5;
  int cur = 0;
  for (int t=0; t<nt; ++t){
    if (t+1 < nt) STAGE(cur^1, (t+1)<<5);
    bf16x8 af[4], bfr[4];
    #pragma unroll
    for (int i=0;i<4;i++){
      int row = wr*64 + i*16 + llo;
      int slot = lhi ^ ((row>>1)&3);
      af[i] = *(const bf16x8*)&As[cur][row*32 + slot*8];
    }
    #pragma unroll
    for (int j=0;j<4;j++){
      int row = wc*64 + j*16 + llo;
      int slot = lhi ^ ((row>>1)&3);
      bfr[j] = *(const bf16x8*)&Bs[cur][row*32 + slot*8];
    }
    #pragma unroll
    for (int i=0;i<4;i++)
      #pragma unroll
      for (int j=0;j<4;j++)
        acc[i][j] = __builtin_amdgcn_mfma_f32_16x16x32_bf16(af[i], bfr[j], acc[i][j], 0,0,0);
    __syncthreads();
    cur ^= 1;
  }

  int m0 = tm*256 + wr*64, n0 = tn*128 + wc*64;
  #pragma unroll
  for (int i=0;i<4;i++){
    #pragma unroll
    for (int j=0;j<4;j++){
      int gn = n0 + j*16 + llo;
      float vv[4];
      #pragma unroll
      for (int rr=0;rr<4;rr++){
        int gm = m0 + i*16 + lhi*4 + rr;
        float v = acc[i][j][rr];
        if (b0){
          const float* bp = (gn < 512) ? b0 : ((gn < 1024) ? b1 : b2);
          v += bp[gn & 511];
        }
        vv[rr] = v;
      }
      int gm0 = m0 + i*16 + lhi*4;
      if (mode == 1){
        int seg = gn >> 9, cn = gn & 511;
        int h = cn >> 6, dd = cn & 63;
        int bb = gm0 / S_, ss0 = gm0 - bb*S_;
        if (seg == vseg){
          bf16x4 v4;
          #pragma unroll
          for (int rr=0;rr<4;rr++) v4[rr] = (bf16)vv[rr];
          *(bf16x4*)&vt[((size_t)(bb*H_ + h)*DH_ + dd)*S_ + ss0] = v4;
        } else {
          bf16* hp = (seg == 0) ? o0 : o1b;
          #pragma unroll
          for (int rr=0;rr<4;rr++)
            hp[(((size_t)(bb*H_ + h))*S_ + ss0 + rr)*DH_ + dd] = (bf16)vv[rr];
        }
      } else {
        #pragma unroll
        for (int rr=0;rr<4;rr++){
          int gm = gm0 + rr;
          float v = vv[rr];
          if (relu) v = fmaxf(v, 0.f);
          o0[(size_t)gm*N + gn] = (bf16)v;
        }
      }
    }
  }
}

// ---------------- flash attention (round-8 proven): XOR-swizzled LDS, T14 split-stage,
// wave-private Ps, XCD-affinity block map.
__global__ __launch_bounds__(256,4) void attn(
    const bf16* __restrict__ Q, const bf16* __restrict__ Kx,
    const bf16* __restrict__ Vt, bf16* __restrict__ out, int causal)
{
  __shared__ bf16 Ks[64*64];
  __shared__ bf16 Vs[64*64];
  __shared__ bf16 Ps[4][16*64];
  int bid = blockIdx.x;
  int bh = bid & 255;
  int qb = bid >> 8;
  int b = bh >> 3, h = bh & 7;
  int tid = threadIdx.x, wave = tid>>6, lane = tid&63;
  int lhi = lane>>4, llo = lane&15;
  int l7 = llo & 7;
  const bf16* Qb = Q  + (size_t)bh*S_*DH_;
  const bf16* Kb = Kx + (size_t)bh*S_*DH_;
  const bf16* Vb = Vt + (size_t)bh*DH_*S_;

  bf16x8 qf[2];
  #pragma unroll
  for (int f=0; f<2; f++)
    qf[f] = *(const bf16x8*)&Qb[(size_t)(qb*64 + wave*16 + llo)*DH_ + f*32 + lhi*8];

  f32x4 oacc[4];
  #pragma unroll
  for (int f=0; f<4; f++) oacc[f] = (f32x4){0.f,0.f,0.f,0.f};
  float mrow[4], lrow4[4];
  #pragma unroll
  for (int r=0;r<4;r++){ mrow[r] = -1e9f; lrow4[r] = 0.f; }

  int KT = causal ? (qb+1) : (S_/64);

  int srow0 = tid>>3, sslot = tid&7;
  bf16x8 kreg[2], vreg[2];

  auto issue = [&](int kb){
    const bf16* kt0 = Kb + (size_t)kb*64*DH_;
    #pragma unroll
    for (int s=0;s<2;s++){
      int row = s*32 + srow0;
      kreg[s] = *(const bf16x8*)&kt0[(size_t)row*64 + sslot*8];
      vreg[s] = *(const bf16x8*)&Vb[(size_t)row*S_ + (size_t)kb*64 + sslot*8];
    }
  };
  issue(0);

  for (int kb=0; kb<KT; kb++){
    #pragma unroll
    for (int s=0;s<2;s++){
      int row = s*32 + srow0;
      int sl = sslot ^ (row&7);
      *(bf16x8*)&Ks[row*64 + sl*8] = kreg[s];
      *(bf16x8*)&Vs[row*64 + sl*8] = vreg[s];
    }
    __syncthreads();

    f32x4 sc[4];
    #pragma unroll
    for (int f=0; f<4; f++){
      f32x4 z = (f32x4){0.f,0.f,0.f,0.f};
      #pragma unroll
      for (int ks=0; ks<2; ks++){
        int row = f*16 + llo;
        int slot = (ks*4 + lhi) ^ (row&7);
        bf16x8 kf = *(const bf16x8*)&Ks[row*64 + slot*8];
        z = __builtin_amdgcn_mfma_f32_16x16x32_bf16(qf[ks], kf, z, 0,0,0);
      }
      sc[f] = z;
    }
    #pragma unroll
    for (int f=0; f<4; f++)
      #pragma unroll
      for (int r=0;r<4;r++){
        float v = sc[f][r]*0.125f;
        if (causal && kb==KT-1){
          int gcol = kb*64 + f*16 + llo;
          int grow = qb*64 + wave*16 + lhi*4 + r;
          if (gcol > grow) v = -1e9f;
        }
        sc[f][r] = v;
      }

    float alpha[4], psum[4];
    #pragma unroll
    for (int r=0;r<4;r++){
      float vm = fmaxf(fmaxf(sc[0][r],sc[1][r]), fmaxf(sc[2][r],sc[3][r]));
      #pragma unroll
      for (int msk=1; msk<16; msk<<=1) vm = fmaxf(vm, __shfl_xor(vm, msk));
      float mn = fmaxf(mrow[r], vm);
      alpha[r] = __expf(mrow[r]-mn);
      mrow[r]  = mn;
      psum[r]  = 0.f;
    }
    #pragma unroll
    for (int f=0; f<4; f++)
      #pragma unroll
      for (int r=0;r<4;r++){
        float p = __expf(sc[f][r]-mrow[r]);
        psum[r] += p;
        int row = lhi*4 + r;
        int slot = (f*2 + (llo>>3)) ^ (row&7);
        Ps[wave][row*64 + slot*8 + l7] = (bf16)p;
      }
    #pragma unroll
    for (int r=0;r<4;r++){
      float s = psum[r];
      #pragma unroll
      for (int msk=1; msk<16; msk<<=1) s += __shfl_xor(s, msk);
      lrow4[r] = lrow4[r]*alpha[r] + s;
      #pragma unroll
      for (int f=0; f<4; f++) oacc[f][r] *= alpha[r];
    }

    if (kb+1 < KT) issue(kb+1);

    asm volatile("s_waitcnt lgkmcnt(0)" ::: "memory");
    __builtin_amdgcn_sched_barrier(0);

    #pragma unroll
    for (int ks=0; ks<2; ks++){
      int pslot = (ks*4 + lhi) ^ l7;
      bf16x8 pf = *(const bf16x8*)&Ps[wave][llo*64 + pslot*8];
      #pragma unroll
      for (int f2=0; f2<4; f2++){
        int row = f2*16 + llo;
        int slot = (ks*4 + lhi) ^ (row&7);
        bf16x8 vf = *(const bf16x8*)&Vs[row*64 + slot*8];
        oacc[f2] = __builtin_amdgcn_mfma_f32_16x16x32_bf16(pf, vf, oacc[f2], 0,0,0);
      }
    }
    __syncthreads();
  }

  int qg = qb*64 + wave*16;
  #pragma unroll
  for (int f2=0; f2<4; f2++)
    #pragma unroll
    for (int r=0;r<4;r++){
      int row = qg + lhi*4 + r;
      int dd  = f2*16 + llo;
      out[((size_t)(b*S_ + row))*D_ + h*DH_ + dd] = (bf16)(oacc[f2][r] / lrow4[r]);
    }
}

// ------------------------------------------------------------------
extern "C" void kernel_launch(void* const* d_in, const int* in_sizes, int n_in,
                              void* d_out, int out_size, void* d_ws, size_t ws_size,
                              hipStream_t stream)
{
  (void)in_sizes; (void)n_in; (void)out_size; (void)ws_size;
  const float* enc = (const float*)d_in[0];
  const float* x2  = (const float*)d_in[1];
  const float* bq1 = (const float*)d_in[3];
  const float* bk1 = (const float*)d_in[5];
  const float* bv1 = (const float*)d_in[7];
  const float* bo1 = (const float*)d_in[9];
  const float* bq2 = (const float*)d_in[11];
  const float* bk2 = (const float*)d_in[13];
  const float* bv2 = (const float*)d_in[15];
  const float* bo2 = (const float*)d_in[17];
  float* outp = (float*)d_out;

  char* ws = (char*)d_ws;
  size_t off = 0;
  auto alloc = [&](size_t bytes)->void*{ void* p = ws + off; off += (bytes+255)&~(size_t)255; return p; };
  bf16* Wt8   = (bf16*)alloc((size_t)8*512*512*2);
  bf16* Wff1t = (bf16*)alloc((size_t)DFF_*D_*2);
  bf16* Wff2t = (bf16*)alloc((size_t)D_*DFF_*2);
  float* bnsc = (float*)alloc(4*512*4);
  float* bnsh = (float*)alloc(4*512*4);
  size_t actB = (size_t)NTOK*D_*2;
  bf16* X2b  = (bf16*)alloc(actB);
  bf16* Abuf = (bf16*)alloc(actB);
  bf16* Bbuf = (bf16*)alloc(actB);
  bf16* Cbuf = (bf16*)alloc(actB);
  bf16* Dv   = (bf16*)alloc(actB);
  bf16* E1   = (bf16*)alloc(actB);
  bf16* E2   = (bf16*)alloc(actB);
  bf16* E3   = E2;                   // cross_out bf16 (E2 dead after q2kv2)
  bf16* Fbuf = Abuf;                 // ff1 [NTOK,DFF] overlays Abuf..Dv

  bf16* Wtq1 = Wt8 + 0*262144;   // [1536,512] = q1|k1|v1
  bf16* Wto1 = Wt8 + 3*262144;
  bf16* Wtq2 = Wt8 + 4*262144;   // [1536,512] = q2|k2|v2
  bf16* Wto2 = Wt8 + 7*262144;

  PrepArgs pa;
  pa.w8[0]=(const float*)d_in[2];  pa.w8[1]=(const float*)d_in[4];
  pa.w8[2]=(const float*)d_in[6];  pa.w8[3]=(const float*)d_in[8];
  pa.w8[4]=(const float*)d_in[10]; pa.w8[5]=(const float*)d_in[12];
  pa.w8[6]=(const float*)d_in[14]; pa.w8[7]=(const float*)d_in[16];
  pa.wff1=(const float*)d_in[18];  pa.wff2=(const float*)d_in[19];
  for (int i=0;i<16;i++) pa.bn[i] = (const float*)d_in[20+i];
  prep_all<<<1032,256,0,stream>>>(pa, Wt8, Wff1t, Wff2t, bnsc, bnsh);
  cvt2<<<dim3(NTOK*D_/4/256, 2),256,0,stream>>>(enc, x2, bnsc+512, bnsh+512, E2, X2b);

  auto gemm = [&](const bf16* Am, const bf16* W, const float* bb0,
                  const bf16* residb, const float* sc, const float* sh,
                  bf16* oo0, float* of, bf16* pre, int N, int K, int relu){
    gemm_bt<<<(NTOK/64)*(N/128), 256, 0, stream>>>(Am, W, bb0, residb, sc, sh,
                                                   oo0, of, pre, NTOK, N, K, relu);
  };
  auto gemm2 = [&](const bf16* Am, const bf16* A2, int tnA, const bf16* W,
                   const float* bb0, const float* bb1, const float* bb2,
                   bf16* oo0, bf16* oo1, bf16* vt, int vseg,
                   int N, int K, int relu, int mode){
    gemm_bt2<<<(NTOK/256)*(N/128), 512, 0, stream>>>(Am, A2, tnA, W, bb0, bb1, bb2,
                                                     oo0, oo1, vt, vseg,
                                                     NTOK, N, K, relu, mode);
  };

  // ---- self-attention (causal): fused QKV projection; V written transposed ----
  gemm2(X2b, nullptr, 0, Wtq1, bq1, bk1, bv1, Abuf, Bbuf, Dv, 2, 1536, 512, 0, 1);
  attn<<<(S_/64)*B_*H_, 256, 0, stream>>>(Abuf, Bbuf, Dv, Cbuf, 1);
  // xn = bn1(attn@Wo1 + bo1 + x2) -> E1
  gemm(Cbuf, Wto1, bo1, X2b, bnsc+0, bnsh+0, E1, nullptr, nullptr, 512, 512, 0);

  // ---- cross-attention: merged q2(E1) + k2,v2(E2) in one N=1536 launch ----
  gemm2(E1, E2, 4, Wtq2, bq2, bk2, bv2, Abuf, Bbuf, Dv, 2, 1536, 512, 0, 1);
  attn<<<(S_/64)*B_*H_, 256, 0, stream>>>(Abuf, Bbuf, Dv, Cbuf, 0);
  // cross_out(bf16) -> E3 (pre-bn); x3 = bn3(cross_out) -> E1
  gemm(Cbuf, Wto2, bo2, X2b, bnsc+2*512, bnsh+2*512, E1, nullptr, E3, 512, 512, 0);

  // ---- FFN ----
  gemm2(E1, nullptr, 0, Wff1t, nullptr, nullptr, nullptr, Fbuf, nullptr, nullptr, -1,
        DFF_, 512, 1, 0);
  // out = bn4(ff1@Wff2 + cross_out)
  gemm(Fbuf, Wff2t, nullptr, E3, bnsc+3*512, bnsh+3*512, nullptr, outp, nullptr, 512, DFF_, 0);
}

// Round 14
// 306.635 us; speedup vs baseline: 1.8062x; 1.8062x over previous
//
#include <hip/hip_runtime.h>
#include <cstdint>
#include <cstddef>

typedef __bf16 bf16;
typedef __bf16 bf16x8 __attribute__((ext_vector_type(8)));
typedef __bf16 bf16x4 __attribute__((ext_vector_type(4)));
typedef float  f32x4  __attribute__((ext_vector_type(4)));

#define B_   32
#define S_   384
#define D_   512
#define H_   8
#define DH_  64
#define DFF_ 2048
#define NTOK (B_*S_)

__device__ __forceinline__ void gload16(const void* g, void* l){
  __builtin_amdgcn_global_load_lds((__attribute__((address_space(1))) uint32_t*)(g),
                                   (__attribute__((address_space(3))) uint32_t*)(l), 16, 0, 0);
}

// ---------------- fused prep: 10 weight transposes (fp32 [K,N] -> bf16 [N,K]) + bn_prep ----------------
struct PrepArgs { const float* w8[8]; const float* wff1; const float* wff2; const float* bn[16]; };
__global__ __launch_bounds__(256) void prep_all(PrepArgs pa, bf16* Wt8, bf16* Wff1t, bf16* Wff2t,
                                                float* sc, float* sh){
  __shared__ float t[64][65];
  int id = blockIdx.x;
  if (id < 1024){
    const float* src; bf16* dst; int R, C, tr, tc;
    if (id < 512){
      int w = id >> 6, tl = id & 63;
      src = pa.w8[w]; dst = Wt8 + (size_t)w*262144; R = 512; C = 512;
      tr = (tl>>3)*64; tc = (tl&7)*64;
    } else if (id < 768){
      int tl = id - 512;                       // Wff1 [512,2048] -> [2048,512]
      src = pa.wff1; dst = Wff1t; R = 512; C = 2048;
      tr = (tl>>5)*64; tc = (tl&31)*64;
    } else {
      int tl = id - 768;                       // Wff2 [2048,512] -> [512,2048]
      src = pa.wff2; dst = Wff2t; R = 2048; C = 512;
      tr = (tl>>3)*64; tc = (tl&7)*64;
    }
    for (int i=threadIdx.x; i<4096; i+=256){ int r=i>>6, c=i&63; t[r][c] = src[(size_t)(tr+r)*C + tc+c]; }
    __syncthreads();
    for (int i=threadIdx.x; i<4096; i+=256){ int c=i>>6, r=i&63; dst[(size_t)(tc+c)*R + tr+r] = (bf16)t[r][c]; }
  } else {
    int t2 = id - 1024;                        // 8 blocks: 4 bns x 2 halves
    int i = t2 >> 1, half = t2 & 1;
    int n = half*256 + threadIdx.x;
    float g = pa.bn[i*4+0][n], b = pa.bn[i*4+1][n], m = pa.bn[i*4+2][n], v = pa.bn[i*4+3][n];
    float s = g * rsqrtf(v + 1e-3f);
    sc[i*512+n] = s; sh[i*512+n] = b - m*s;
  }
}

// fused: y=0 -> bn2(enc) -> E2 ; y=1 -> bf16(x2) -> X2b
__global__ __launch_bounds__(256) void cvt2(const float* __restrict__ enc, const float* __restrict__ x2,
                                            const float* __restrict__ sc, const float* __restrict__ sh,
                                            bf16* __restrict__ E2, bf16* __restrict__ X2b){
  size_t e0 = ((size_t)blockIdx.x*256 + threadIdx.x)*4;
  if (blockIdx.y == 0){
    int n0 = (int)(e0 & (D_-1));
    f32x4 xv = *(const f32x4*)(enc + e0);
    bf16x4 ov;
    #pragma unroll
    for (int j=0;j<4;j++) ov[j] = (bf16)(xv[j]*sc[n0+j] + sh[n0+j]);
    *(bf16x4*)(E2 + e0) = ov;
  } else {
    f32x4 xv = *(const f32x4*)(x2 + e0);
    bf16x4 ov;
    #pragma unroll
    for (int j=0;j<4;j++) ov[j] = (bf16)xv[j];
    *(bf16x4*)(X2b + e0) = ov;
  }
}

// ---------------- 64x128 GEMM (N=512 shapes: o1,o2,ff2), BK=64, 2-phase dbuf, XOR swizzle ------------
__global__ __launch_bounds__(256,3) void gemm_bt(
    const bf16* __restrict__ A, const bf16* __restrict__ Wt,
    const float* __restrict__ b0,
    const bf16* __restrict__ residb,
    const float* __restrict__ bsc, const float* __restrict__ bsh,
    bf16* __restrict__ o0,
    float* __restrict__ of, bf16* __restrict__ pre,
    int M, int N, int K, int relu)
{
  __shared__ bf16 As[2][64*64];
  __shared__ bf16 Bs[2][128*64];
  int nwg = gridDim.x;
  int cpx = nwg >> 3;
  int bid = blockIdx.x;
  int swz = (bid & 7)*cpx + (bid >> 3);
  int tiles_n = N >> 7;
  int tm = swz / tiles_n, tn = swz - tm*tiles_n;

  int tid = threadIdx.x, wave = tid>>6, lane = tid&63;
  int lhi = lane>>4, llo = lane&15;
  int lrow = lane>>3, lcol = lane&7;
  int wr = wave>>1, wc = wave&1;

  f32x4 acc[2][4];
  #pragma unroll
  for (int i=0;i<2;i++)
    #pragma unroll
    for (int j=0;j<4;j++) acc[i][j] = (f32x4){0.f,0.f,0.f,0.f};

  const bf16* Abase = A  + (size_t)(tm*64)  * K;
  const bf16* Bbase = Wt + (size_t)(tn*128) * K;

  int arow0 = wave*16, brow0 = wave*32;

  auto STAGE = [&](int buf, int kt){
    #pragma unroll
    for (int q=0;q<2;q++){
      int r = arow0 + q*8 + lrow;
      int s = lcol ^ (r&7);
      gload16(Abase + (size_t)r*K + kt + s*8, (char*)&As[buf][0] + wave*2048 + q*1024);
    }
    #pragma unroll
    for (int q=0;q<4;q++){
      int r = brow0 + q*8 + lrow;
      int s = lcol ^ (r&7);
      gload16(Bbase + (size_t)r*K + kt + s*8, (char*)&Bs[buf][0] + wave*4096 + q*1024);
    }
  };

  STAGE(0, 0);
  __syncthreads();
  int nt = K >> 6;
  int cur = 0;
  for (int t=0; t<nt; ++t){
    if (t+1 < nt) STAGE(cur^1, (t+1)<<6);
    #pragma unroll
    for (int ks=0; ks<2; ks++){
      bf16x8 af[2], bfr[4];
      #pragma unroll
      for (int i=0;i<2;i++){
        int row = wr*32 + i*16 + llo;
        int slot = (ks*4 + lhi) ^ (row&7);
        af[i] = *(const bf16x8*)&As[cur][row*64 + slot*8];
      }
      #pragma unroll
      for (int j=0;j<4;j++){
        int row = wc*64 + j*16 + llo;
        int slot = (ks*4 + lhi) ^ (row&7);
        bfr[j] = *(const bf16x8*)&Bs[cur][row*64 + slot*8];
      }
      #pragma unroll
      for (int i=0;i<2;i++)
        #pragma unroll
        for (int j=0;j<4;j++)
          acc[i][j] = __builtin_amdgcn_mfma_f32_16x16x32_bf16(af[i], bfr[j], acc[i][j], 0,0,0);
    }
    __syncthreads();
    cur ^= 1;
  }

  int m0 = tm*64 + wr*32, n0 = tn*128 + wc*64;
  #pragma unroll
  for (int i=0;i<2;i++){
    #pragma unroll
    for (int j=0;j<4;j++){
      int gn = n0 + j*16 + llo;
      #pragma unroll
      for (int rr=0;rr<4;rr++){
        int gm = m0 + i*16 + lhi*4 + rr;
        float v = acc[i][j][rr];
        if (b0) v += b0[gn & 511];
        if (residb) v += (float)residb[(size_t)gm*N + gn];
        if (pre)  pre[(size_t)gm*N + gn] = (bf16)v;
        if (bsc)  v = v*bsc[gn & 511] + bsh[gn & 511];
        if (relu) v = fmaxf(v, 0.f);
        if (of) of[(size_t)gm*N + gn] = v;
        else    o0[(size_t)gm*N + gn] = (bf16)v;
      }
    }
  }
}

// ---------------- 128x128 GEMM (big shapes: QKV, q2kv2, ff1), BK=32, 2-phase dbuf ----------------
// 64 B rows -> swizzle (r>>1)&3 (conflicts measured 0).  A-select: tiles tn >= tnA read A2.
__global__ __launch_bounds__(256,4) void gemm_bt2(
    const bf16* __restrict__ A, const bf16* __restrict__ A2, int tnA,
    const bf16* __restrict__ Wt,
    const float* __restrict__ b0, const float* __restrict__ b1, const float* __restrict__ b2,
    bf16* __restrict__ o0, bf16* __restrict__ o1b,
    bf16* __restrict__ vt, int vseg,
    int M, int N, int K, int relu, int mode)
{
  __shared__ bf16 As[2][128*32];
  __shared__ bf16 Bs[2][128*32];
  int nwg = gridDim.x;
  int cpx = nwg >> 3;
  int bid = blockIdx.x;
  int swz = (bid & 7)*cpx + (bid >> 3);
  int tiles_n = N >> 7;
  int tm = swz / tiles_n, tn = swz - tm*tiles_n;

  int tid = threadIdx.x, wave = tid>>6, lane = tid&63;
  int lhi = lane>>4, llo = lane&15;
  int srow = lane>>2, sslot = lane&3;
  int wr = wave>>1, wc = wave&1;

  f32x4 acc[4][4];
  #pragma unroll
  for (int i=0;i<4;i++)
    #pragma unroll
    for (int j=0;j<4;j++) acc[i][j] = (f32x4){0.f,0.f,0.f,0.f};

  const bf16* Asrc = (A2 && tn >= tnA) ? A2 : A;
  const bf16* Abase = Asrc + (size_t)(tm*128) * K;
  const bf16* Bbase = Wt   + (size_t)(tn*128) * K;

  auto STAGE = [&](int buf, int kt){
    #pragma unroll
    for (int q=0;q<2;q++){
      int r = wave*32 + q*16 + srow;
      int s = sslot ^ ((r>>1)&3);
      gload16(Abase + (size_t)r*K + kt + s*8, (char*)&As[buf][0] + wave*2048 + q*1024);
    }
    #pragma unroll
    for (int q=0;q<2;q++){
      int r = wave*32 + q*16 + srow;
      int s = sslot ^ ((r>>1)&3);
      gload16(Bbase + (size_t)r*K + kt + s*8, (char*)&Bs[buf][0] + wave*2048 + q*1024);
    }
  };

  STAGE(0, 0);
  __syncthreads();
  int nt = K >> 5;
  int cur = 0;
  for (int t=0; t<nt; ++t){
    if (t+1 < nt) STAGE(cur^1, (t+1)<<5);
    bf16x8 af[4], bfr[4];
    #pragma unroll
    for (int i=0;i<4;i++){
      int row = wr*64 + i*16 + llo;
      int slot = lhi ^ ((row>>1)&3);
      af[i] = *(const bf16x8*)&As[cur][row*32 + slot*8];
    }
    #pragma unroll
    for (int j=0;j<4;j++){
      int row = wc*64 + j*16 + llo;
      int slot = lhi ^ ((row>>1)&3);
      bfr[j] = *(const bf16x8*)&Bs[cur][row*32 + slot*8];
    }
    #pragma unroll
    for (int i=0;i<4;i++)
      #pragma unroll
      for (int j=0;j<4;j++)
        acc[i][j] = __builtin_amdgcn_mfma_f32_16x16x32_bf16(af[i], bfr[j], acc[i][j], 0,0,0);
    __syncthreads();
    cur ^= 1;
  }

  int m0 = tm*128 + wr*64, n0 = tn*128 + wc*64;
  #pragma unroll
  for (int i=0;i<4;i++){
    #pragma unroll
    for (int j=0;j<4;j++){
      int gn = n0 + j*16 + llo;
      float vv[4];
      #pragma unroll
      for (int rr=0;rr<4;rr++){
        int gm = m0 + i*16 + lhi*4 + rr;
        float v = acc[i][j][rr];
        if (b0){
          const float* bp = (gn < 512) ? b0 : ((gn < 1024) ? b1 : b2);
          v += bp[gn & 511];
        }
        vv[rr] = v;
      }
      int gm0 = m0 + i*16 + lhi*4;
      if (mode == 1){
        int seg = gn >> 9, cn = gn & 511;
        int h = cn >> 6, dd = cn & 63;
        int bb = gm0 / S_, ss0 = gm0 - bb*S_;
        if (seg == vseg){
          bf16x4 v4;
          #pragma unroll
          for (int rr=0;rr<4;rr++) v4[rr] = (bf16)vv[rr];
          *(bf16x4*)&vt[((size_t)(bb*H_ + h)*DH_ + dd)*S_ + ss0] = v4;
        } else {
          bf16* hp = (seg == 0) ? o0 : o1b;
          #pragma unroll
          for (int rr=0;rr<4;rr++)
            hp[(((size_t)(bb*H_ + h))*S_ + ss0 + rr)*DH_ + dd] = (bf16)vv[rr];
        }
      } else {
        #pragma unroll
        for (int rr=0;rr<4;rr++){
          int gm = gm0 + rr;
          float v = vv[rr];
          if (relu) v = fmaxf(v, 0.f);
          o0[(size_t)gm*N + gn] = (bf16)v;
        }
      }
    }
  }
}

// ---------------- flash attention (round-8 proven): XOR-swizzled LDS, T14 split-stage,
// wave-private Ps, XCD-affinity block map.
__global__ __launch_bounds__(256,4) void attn(
    const bf16* __restrict__ Q, const bf16* __restrict__ Kx,
    const bf16* __restrict__ Vt, bf16* __restrict__ out, int causal)
{
  __shared__ bf16 Ks[64*64];
  __shared__ bf16 Vs[64*64];
  __shared__ bf16 Ps[4][16*64];
  int bid = blockIdx.x;
  int bh = bid & 255;
  int qb = bid >> 8;
  int b = bh >> 3, h = bh & 7;
  int tid = threadIdx.x, wave = tid>>6, lane = tid&63;
  int lhi = lane>>4, llo = lane&15;
  int l7 = llo & 7;
  const bf16* Qb = Q  + (size_t)bh*S_*DH_;
  const bf16* Kb = Kx + (size_t)bh*S_*DH_;
  const bf16* Vb = Vt + (size_t)bh*DH_*S_;

  bf16x8 qf[2];
  #pragma unroll
  for (int f=0; f<2; f++)
    qf[f] = *(const bf16x8*)&Qb[(size_t)(qb*64 + wave*16 + llo)*DH_ + f*32 + lhi*8];

  f32x4 oacc[4];
  #pragma unroll
  for (int f=0; f<4; f++) oacc[f] = (f32x4){0.f,0.f,0.f,0.f};
  float mrow[4], lrow4[4];
  #pragma unroll
  for (int r=0;r<4;r++){ mrow[r] = -1e9f; lrow4[r] = 0.f; }

  int KT = causal ? (qb+1) : (S_/64);

  int srow0 = tid>>3, sslot = tid&7;
  bf16x8 kreg[2], vreg[2];

  auto issue = [&](int kb){
    const bf16* kt0 = Kb + (size_t)kb*64*DH_;
    #pragma unroll
    for (int s=0;s<2;s++){
      int row = s*32 + srow0;
      kreg[s] = *(const bf16x8*)&kt0[(size_t)row*64 + sslot*8];
      vreg[s] = *(const bf16x8*)&Vb[(size_t)row*S_ + (size_t)kb*64 + sslot*8];
    }
  };
  issue(0);

  for (int kb=0; kb<KT; kb++){
    #pragma unroll
    for (int s=0;s<2;s++){
      int row = s*32 + srow0;
      int sl = sslot ^ (row&7);
      *(bf16x8*)&Ks[row*64 + sl*8] = kreg[s];
      *(bf16x8*)&Vs[row*64 + sl*8] = vreg[s];
    }
    __syncthreads();

    f32x4 sc[4];
    #pragma unroll
    for (int f=0; f<4; f++){
      f32x4 z = (f32x4){0.f,0.f,0.f,0.f};
      #pragma unroll
      for (int ks=0; ks<2; ks++){
        int row = f*16 + llo;
        int slot = (ks*4 + lhi) ^ (row&7);
        bf16x8 kf = *(const bf16x8*)&Ks[row*64 + slot*8];
        z = __builtin_amdgcn_mfma_f32_16x16x32_bf16(qf[ks], kf, z, 0,0,0);
      }
      sc[f] = z;
    }
    #pragma unroll
    for (int f=0; f<4; f++)
      #pragma unroll
      for (int r=0;r<4;r++){
        float v = sc[f][r]*0.125f;
        if (causal && kb==KT-1){
          int gcol = kb*64 + f*16 + llo;
          int grow = qb*64 + wave*16 + lhi*4 + r;
          if (gcol > grow) v = -1e9f;
        }
        sc[f][r] = v;
      }

    float alpha[4], psum[4];
    #pragma unroll
    for (int r=0;r<4;r++){
      float vm = fmaxf(fmaxf(sc[0][r],sc[1][r]), fmaxf(sc[2][r],sc[3][r]));
      #pragma unroll
      for (int msk=1; msk<16; msk<<=1) vm = fmaxf(vm, __shfl_xor(vm, msk));
      float mn = fmaxf(mrow[r], vm);
      alpha[r] = __expf(mrow[r]-mn);
      mrow[r]  = mn;
      psum[r]  = 0.f;
    }
    #pragma unroll
    for (int f=0; f<4; f++)
      #pragma unroll
      for (int r=0;r<4;r++){
        float p = __expf(sc[f][r]-mrow[r]);
        psum[r] += p;
        int row = lhi*4 + r;
        int slot = (f*2 + (llo>>3)) ^ (row&7);
        Ps[wave][row*64 + slot*8 + l7] = (bf16)p;
      }
    #pragma unroll
    for (int r=0;r<4;r++){
      float s = psum[r];
      #pragma unroll
      for (int msk=1; msk<16; msk<<=1) s += __shfl_xor(s, msk);
      lrow4[r] = lrow4[r]*alpha[r] + s;
      #pragma unroll
      for (int f=0; f<4; f++) oacc[f][r] *= alpha[r];
    }

    if (kb+1 < KT) issue(kb+1);

    asm volatile("s_waitcnt lgkmcnt(0)" ::: "memory");
    __builtin_amdgcn_sched_barrier(0);

    #pragma unroll
    for (int ks=0; ks<2; ks++){
      int pslot = (ks*4 + lhi) ^ l7;
      bf16x8 pf = *(const bf16x8*)&Ps[wave][llo*64 + pslot*8];
      #pragma unroll
      for (int f2=0; f2<4; f2++){
        int row = f2*16 + llo;
        int slot = (ks*4 + lhi) ^ (row&7);
        bf16x8 vf = *(const bf16x8*)&Vs[row*64 + slot*8];
        oacc[f2] = __builtin_amdgcn_mfma_f32_16x16x32_bf16(pf, vf, oacc[f2], 0,0,0);
      }
    }
    __syncthreads();
  }

  int qg = qb*64 + wave*16;
  #pragma unroll
  for (int f2=0; f2<4; f2++)
    #pragma unroll
    for (int r=0;r<4;r++){
      int row = qg + lhi*4 + r;
      int dd  = f2*16 + llo;
      out[((size_t)(b*S_ + row))*D_ + h*DH_ + dd] = (bf16)(oacc[f2][r] / lrow4[r]);
    }
}

// ------------------------------------------------------------------
extern "C" void kernel_launch(void* const* d_in, const int* in_sizes, int n_in,
                              void* d_out, int out_size, void* d_ws, size_t ws_size,
                              hipStream_t stream)
{
  (void)in_sizes; (void)n_in; (void)out_size; (void)ws_size;
  const float* enc = (const float*)d_in[0];
  const float* x2  = (const float*)d_in[1];
  const float* bq1 = (const float*)d_in[3];
  const float* bk1 = (const float*)d_in[5];
  const float* bv1 = (const float*)d_in[7];
  const float* bo1 = (const float*)d_in[9];
  const float* bq2 = (const float*)d_in[11];
  const float* bk2 = (const float*)d_in[13];
  const float* bv2 = (const float*)d_in[15];
  const float* bo2 = (const float*)d_in[17];
  float* outp = (float*)d_out;

  char* ws = (char*)d_ws;
  size_t off = 0;
  auto alloc = [&](size_t bytes)->void*{ void* p = ws + off; off += (bytes+255)&~(size_t)255; return p; };
  bf16* Wt8   = (bf16*)alloc((size_t)8*512*512*2);
  bf16* Wff1t = (bf16*)alloc((size_t)DFF_*D_*2);
  bf16* Wff2t = (bf16*)alloc((size_t)D_*DFF_*2);
  float* bnsc = (float*)alloc(4*512*4);
  float* bnsh = (float*)alloc(4*512*4);
  size_t actB = (size_t)NTOK*D_*2;
  bf16* X2b  = (bf16*)alloc(actB);
  bf16* Abuf = (bf16*)alloc(actB);
  bf16* Bbuf = (bf16*)alloc(actB);
  bf16* Cbuf = (bf16*)alloc(actB);
  bf16* Dv   = (bf16*)alloc(actB);
  bf16* E1   = (bf16*)alloc(actB);
  bf16* E2   = (bf16*)alloc(actB);
  bf16* E3   = E2;                   // cross_out bf16 (E2 dead after q2kv2)
  bf16* Fbuf = Abuf;                 // ff1 [NTOK,DFF] overlays Abuf..Dv

  bf16* Wtq1 = Wt8 + 0*262144;   // [1536,512] = q1|k1|v1
  bf16* Wto1 = Wt8 + 3*262144;
  bf16* Wtq2 = Wt8 + 4*262144;   // [1536,512] = q2|k2|v2
  bf16* Wto2 = Wt8 + 7*262144;

  PrepArgs pa;
  pa.w8[0]=(const float*)d_in[2];  pa.w8[1]=(const float*)d_in[4];
  pa.w8[2]=(const float*)d_in[6];  pa.w8[3]=(const float*)d_in[8];
  pa.w8[4]=(const float*)d_in[10]; pa.w8[5]=(const float*)d_in[12];
  pa.w8[6]=(const float*)d_in[14]; pa.w8[7]=(const float*)d_in[16];
  pa.wff1=(const float*)d_in[18];  pa.wff2=(const float*)d_in[19];
  for (int i=0;i<16;i++) pa.bn[i] = (const float*)d_in[20+i];
  prep_all<<<1032,256,0,stream>>>(pa, Wt8, Wff1t, Wff2t, bnsc, bnsh);
  cvt2<<<dim3(NTOK*D_/4/256, 2),256,0,stream>>>(enc, x2, bnsc+512, bnsh+512, E2, X2b);

  auto gemm = [&](const bf16* Am, const bf16* W, const float* bb0,
                  const bf16* residb, const float* sc, const float* sh,
                  bf16* oo0, float* of, bf16* pre, int N, int K, int relu){
    gemm_bt<<<(NTOK/64)*(N/128), 256, 0, stream>>>(Am, W, bb0, residb, sc, sh,
                                                   oo0, of, pre, NTOK, N, K, relu);
  };
  auto gemm2 = [&](const bf16* Am, const bf16* A2, int tnA, const bf16* W,
                   const float* bb0, const float* bb1, const float* bb2,
                   bf16* oo0, bf16* oo1, bf16* vt, int vseg,
                   int N, int K, int relu, int mode){
    gemm_bt2<<<(NTOK/128)*(N/128), 256, 0, stream>>>(Am, A2, tnA, W, bb0, bb1, bb2,
                                                     oo0, oo1, vt, vseg,
                                                     NTOK, N, K, relu, mode);
  };

  // ---- self-attention (causal): fused QKV projection; V written transposed ----
  gemm2(X2b, nullptr, 0, Wtq1, bq1, bk1, bv1, Abuf, Bbuf, Dv, 2, 1536, 512, 0, 1);
  attn<<<(S_/64)*B_*H_, 256, 0, stream>>>(Abuf, Bbuf, Dv, Cbuf, 1);
  // xn = bn1(attn@Wo1 + bo1 + x2) -> E1
  gemm(Cbuf, Wto1, bo1, X2b, bnsc+0, bnsh+0, E1, nullptr, nullptr, 512, 512, 0);

  // ---- cross-attention: merged q2(E1) + k2,v2(E2) in one N=1536 launch ----
  gemm2(E1, E2, 4, Wtq2, bq2, bk2, bv2, Abuf, Bbuf, Dv, 2, 1536, 512, 0, 1);
  attn<<<(S_/64)*B_*H_, 256, 0, stream>>>(Abuf, Bbuf, Dv, Cbuf, 0);
  // cross_out(bf16) -> E3 (pre-bn); x3 = bn3(cross_out) -> E1
  gemm(Cbuf, Wto2, bo2, X2b, bnsc+2*512, bnsh+2*512, E1, nullptr, E3, 512, 512, 0);

  // ---- FFN ----
  gemm2(E1, nullptr, 0, Wff1t, nullptr, nullptr, nullptr, Fbuf, nullptr, nullptr, -1,
        DFF_, 512, 1, 0);
  // out = bn4(ff1@Wff2 + cross_out)
  gemm(Fbuf, Wff2t, nullptr, E3, bnsc+3*512, bnsh+3*512, nullptr, outp, nullptr, 512, DFF_, 0);
}

// Round 15
// 303.989 us; speedup vs baseline: 1.8219x; 1.0087x over previous
//
#include <hip/hip_runtime.h>
#include <cstdint>
#include <cstddef>

typedef __bf16 bf16;
typedef __bf16 bf16x8 __attribute__((ext_vector_type(8)));
typedef __bf16 bf16x4 __attribute__((ext_vector_type(4)));
typedef float  f32x4  __attribute__((ext_vector_type(4)));

#define B_   32
#define S_   384
#define D_   512
#define H_   8
#define DH_  64
#define DFF_ 2048
#define NTOK (B_*S_)

__device__ __forceinline__ void gload16(const void* g, void* l){
  __builtin_amdgcn_global_load_lds((__attribute__((address_space(1))) uint32_t*)(g),
                                   (__attribute__((address_space(3))) uint32_t*)(l), 16, 0, 0);
}

// ---------------- fused prep: 10 weight transposes + bn_prep + both activation conversions ----------
// blocks 0..1023: transposes; 1024..1031: bn scale/shift tables; 1032..7175: bn2(enc)->E2 (inline
// scale/shift from raw params — no dependency on the bn_prep blocks); 7176..13319: bf16(x2)->X2b.
struct PrepArgs { const float* w8[8]; const float* wff1; const float* wff2; const float* bn[16]; };
__global__ __launch_bounds__(256) void prep_all(PrepArgs pa, bf16* Wt8, bf16* Wff1t, bf16* Wff2t,
                                                float* sc, float* sh,
                                                const float* __restrict__ enc,
                                                const float* __restrict__ x2,
                                                bf16* __restrict__ E2, bf16* __restrict__ X2b){
  __shared__ float t[64][65];
  int id = blockIdx.x;
  if (id < 1024){
    const float* src; bf16* dst; int R, C, tr, tc;
    if (id < 512){
      int w = id >> 6, tl = id & 63;
      src = pa.w8[w]; dst = Wt8 + (size_t)w*262144; R = 512; C = 512;
      tr = (tl>>3)*64; tc = (tl&7)*64;
    } else if (id < 768){
      int tl = id - 512;                       // Wff1 [512,2048] -> [2048,512]
      src = pa.wff1; dst = Wff1t; R = 512; C = 2048;
      tr = (tl>>5)*64; tc = (tl&31)*64;
    } else {
      int tl = id - 768;                       // Wff2 [2048,512] -> [512,2048]
      src = pa.wff2; dst = Wff2t; R = 2048; C = 512;
      tr = (tl>>3)*64; tc = (tl&7)*64;
    }
    for (int i=threadIdx.x; i<4096; i+=256){ int r=i>>6, c=i&63; t[r][c] = src[(size_t)(tr+r)*C + tc+c]; }
    __syncthreads();
    for (int i=threadIdx.x; i<4096; i+=256){ int c=i>>6, r=i&63; dst[(size_t)(tc+c)*R + tr+r] = (bf16)t[r][c]; }
  } else if (id < 1032){
    int t2 = id - 1024;                        // 8 blocks: 4 bns x 2 halves
    int i = t2 >> 1, half = t2 & 1;
    int n = half*256 + threadIdx.x;
    float g = pa.bn[i*4+0][n], b = pa.bn[i*4+1][n], m = pa.bn[i*4+2][n], v = pa.bn[i*4+3][n];
    float s = g * rsqrtf(v + 1e-3f);
    sc[i*512+n] = s; sh[i*512+n] = b - m*s;
  } else if (id < 1032 + 6144){                // y = bn2(enc) -> E2, inline scale/shift
    size_t e0 = ((size_t)(id-1032)*256 + threadIdx.x)*4;
    int n0 = (int)(e0 & (D_-1));
    f32x4 xv = *(const f32x4*)(enc + e0);
    bf16x4 ov;
    #pragma unroll
    for (int j=0;j<4;j++){
      float g = pa.bn[4][n0+j], b = pa.bn[5][n0+j], m = pa.bn[6][n0+j], v = pa.bn[7][n0+j];
      float s = g * rsqrtf(v + 1e-3f);
      ov[j] = (bf16)(xv[j]*s + (b - m*s));
    }
    *(bf16x4*)(E2 + e0) = ov;
  } else {                                     // bf16(x2) -> X2b
    size_t e0 = ((size_t)(id-1032-6144)*256 + threadIdx.x)*4;
    f32x4 xv = *(const f32x4*)(x2 + e0);
    bf16x4 ov;
    #pragma unroll
    for (int j=0;j<4;j++) ov[j] = (bf16)xv[j];
    *(bf16x4*)(X2b + e0) = ov;
  }
}

// ---------------- 64x128 GEMM (N=512 shapes: o1,o2,ff2), BK=64, 2-phase dbuf, XOR swizzle ------------
__global__ __launch_bounds__(256,3) void gemm_bt(
    const bf16* __restrict__ A, const bf16* __restrict__ Wt,
    const float* __restrict__ b0,
    const bf16* __restrict__ residb,
    const float* __restrict__ bsc, const float* __restrict__ bsh,
    bf16* __restrict__ o0,
    float* __restrict__ of, bf16* __restrict__ pre,
    int M, int N, int K, int relu)
{
  __shared__ bf16 As[2][64*64];
  __shared__ bf16 Bs[2][128*64];
  int nwg = gridDim.x;
  int cpx = nwg >> 3;
  int bid = blockIdx.x;
  int swz = (bid & 7)*cpx + (bid >> 3);
  int tiles_n = N >> 7;
  int tm = swz / tiles_n, tn = swz - tm*tiles_n;

  int tid = threadIdx.x, wave = tid>>6, lane = tid&63;
  int lhi = lane>>4, llo = lane&15;
  int lrow = lane>>3, lcol = lane&7;
  int wr = wave>>1, wc = wave&1;

  f32x4 acc[2][4];
  #pragma unroll
  for (int i=0;i<2;i++)
    #pragma unroll
    for (int j=0;j<4;j++) acc[i][j] = (f32x4){0.f,0.f,0.f,0.f};

  const bf16* Abase = A  + (size_t)(tm*64)  * K;
  const bf16* Bbase = Wt + (size_t)(tn*128) * K;

  int arow0 = wave*16, brow0 = wave*32;

  auto STAGE = [&](int buf, int kt){
    #pragma unroll
    for (int q=0;q<2;q++){
      int r = arow0 + q*8 + lrow;
      int s = lcol ^ (r&7);
      gload16(Abase + (size_t)r*K + kt + s*8, (char*)&As[buf][0] + wave*2048 + q*1024);
    }
    #pragma unroll
    for (int q=0;q<4;q++){
      int r = brow0 + q*8 + lrow;
      int s = lcol ^ (r&7);
      gload16(Bbase + (size_t)r*K + kt + s*8, (char*)&Bs[buf][0] + wave*4096 + q*1024);
    }
  };

  STAGE(0, 0);
  __syncthreads();
  int nt = K >> 6;
  int cur = 0;
  for (int t=0; t<nt; ++t){
    if (t+1 < nt) STAGE(cur^1, (t+1)<<6);
    #pragma unroll
    for (int ks=0; ks<2; ks++){
      bf16x8 af[2], bfr[4];
      #pragma unroll
      for (int i=0;i<2;i++){
        int row = wr*32 + i*16 + llo;
        int slot = (ks*4 + lhi) ^ (row&7);
        af[i] = *(const bf16x8*)&As[cur][row*64 + slot*8];
      }
      #pragma unroll
      for (int j=0;j<4;j++){
        int row = wc*64 + j*16 + llo;
        int slot = (ks*4 + lhi) ^ (row&7);
        bfr[j] = *(const bf16x8*)&Bs[cur][row*64 + slot*8];
      }
      #pragma unroll
      for (int i=0;i<2;i++)
        #pragma unroll
        for (int j=0;j<4;j++)
          acc[i][j] = __builtin_amdgcn_mfma_f32_16x16x32_bf16(af[i], bfr[j], acc[i][j], 0,0,0);
    }
    __syncthreads();
    cur ^= 1;
  }

  int m0 = tm*64 + wr*32, n0 = tn*128 + wc*64;
  #pragma unroll
  for (int i=0;i<2;i++){
    #pragma unroll
    for (int j=0;j<4;j++){
      int gn = n0 + j*16 + llo;
      #pragma unroll
      for (int rr=0;rr<4;rr++){
        int gm = m0 + i*16 + lhi*4 + rr;
        float v = acc[i][j][rr];
        if (b0) v += b0[gn & 511];
        if (residb) v += (float)residb[(size_t)gm*N + gn];
        if (pre)  pre[(size_t)gm*N + gn] = (bf16)v;
        if (bsc)  v = v*bsc[gn & 511] + bsh[gn & 511];
        if (relu) v = fmaxf(v, 0.f);
        if (of) of[(size_t)gm*N + gn] = v;
        else    o0[(size_t)gm*N + gn] = (bf16)v;
      }
    }
  }
}

// ---------------- 128x128 GEMM (big shapes: QKV, q2kv2, ff1), BK=32, 2-phase dbuf ----------------
// 64 B rows -> swizzle (r>>1)&3 (conflicts measured 0).  A-select: tiles tn >= tnA read A2.
__global__ __launch_bounds__(256,4) void gemm_bt2(
    const bf16* __restrict__ A, const bf16* __restrict__ A2, int tnA,
    const bf16* __restrict__ Wt,
    const float* __restrict__ b0, const float* __restrict__ b1, const float* __restrict__ b2,
    bf16* __restrict__ o0, bf16* __restrict__ o1b,
    bf16* __restrict__ vt, int vseg,
    int M, int N, int K, int relu, int mode)
{
  __shared__ bf16 As[2][128*32];
  __shared__ bf16 Bs[2][128*32];
  int nwg = gridDim.x;
  int cpx = nwg >> 3;
  int bid = blockIdx.x;
  int swz = (bid & 7)*cpx + (bid >> 3);
  int tiles_n = N >> 7;
  int tm = swz / tiles_n, tn = swz - tm*tiles_n;

  int tid = threadIdx.x, wave = tid>>6, lane = tid&63;
  int lhi = lane>>4, llo = lane&15;
  int srow = lane>>2, sslot = lane&3;
  int wr = wave>>1, wc = wave&1;

  f32x4 acc[4][4];
  #pragma unroll
  for (int i=0;i<4;i++)
    #pragma unroll
    for (int j=0;j<4;j++) acc[i][j] = (f32x4){0.f,0.f,0.f,0.f};

  const bf16* Asrc = (A2 && tn >= tnA) ? A2 : A;
  const bf16* Abase = Asrc + (size_t)(tm*128) * K;
  const bf16* Bbase = Wt   + (size_t)(tn*128) * K;

  auto STAGE = [&](int buf, int kt){
    #pragma unroll
    for (int q=0;q<2;q++){
      int r = wave*32 + q*16 + srow;
      int s = sslot ^ ((r>>1)&3);
      gload16(Abase + (size_t)r*K + kt + s*8, (char*)&As[buf][0] + wave*2048 + q*1024);
    }
    #pragma unroll
    for (int q=0;q<2;q++){
      int r = wave*32 + q*16 + srow;
      int s = sslot ^ ((r>>1)&3);
      gload16(Bbase + (size_t)r*K + kt + s*8, (char*)&Bs[buf][0] + wave*2048 + q*1024);
    }
  };

  STAGE(0, 0);
  __syncthreads();
  int nt = K >> 5;
  int cur = 0;
  for (int t=0; t<nt; ++t){
    if (t+1 < nt) STAGE(cur^1, (t+1)<<5);
    bf16x8 af[4], bfr[4];
    #pragma unroll
    for (int i=0;i<4;i++){
      int row = wr*64 + i*16 + llo;
      int slot = lhi ^ ((row>>1)&3);
      af[i] = *(const bf16x8*)&As[cur][row*32 + slot*8];
    }
    #pragma unroll
    for (int j=0;j<4;j++){
      int row = wc*64 + j*16 + llo;
      int slot = lhi ^ ((row>>1)&3);
      bfr[j] = *(const bf16x8*)&Bs[cur][row*32 + slot*8];
    }
    #pragma unroll
    for (int i=0;i<4;i++)
      #pragma unroll
      for (int j=0;j<4;j++)
        acc[i][j] = __builtin_amdgcn_mfma_f32_16x16x32_bf16(af[i], bfr[j], acc[i][j], 0,0,0);
    __syncthreads();
    cur ^= 1;
  }

  int m0 = tm*128 + wr*64, n0 = tn*128 + wc*64;
  #pragma unroll
  for (int i=0;i<4;i++){
    #pragma unroll
    for (int j=0;j<4;j++){
      int gn = n0 + j*16 + llo;
      float vv[4];
      #pragma unroll
      for (int rr=0;rr<4;rr++){
        int gm = m0 + i*16 + lhi*4 + rr;
        float v = acc[i][j][rr];
        if (b0){
          const float* bp = (gn < 512) ? b0 : ((gn < 1024) ? b1 : b2);
          v += bp[gn & 511];
        }
        vv[rr] = v;
      }
      int gm0 = m0 + i*16 + lhi*4;
      if (mode == 1){
        int seg = gn >> 9, cn = gn & 511;
        int h = cn >> 6, dd = cn & 63;
        int bb = gm0 / S_, ss0 = gm0 - bb*S_;
        if (seg == vseg){
          bf16x4 v4;
          #pragma unroll
          for (int rr=0;rr<4;rr++) v4[rr] = (bf16)vv[rr];
          *(bf16x4*)&vt[((size_t)(bb*H_ + h)*DH_ + dd)*S_ + ss0] = v4;
        } else {
          bf16* hp = (seg == 0) ? o0 : o1b;
          #pragma unroll
          for (int rr=0;rr<4;rr++)
            hp[(((size_t)(bb*H_ + h))*S_ + ss0 + rr)*DH_ + dd] = (bf16)vv[rr];
        }
      } else {
        #pragma unroll
        for (int rr=0;rr<4;rr++){
          int gm = gm0 + rr;
          float v = vv[rr];
          if (relu) v = fmaxf(v, 0.f);
          o0[(size_t)gm*N + gn] = (bf16)v;
        }
      }
    }
  }
}

// ---------------- flash attention: XOR-swizzled LDS, wave-private Ps, XCD-affinity map.
// T14 deepened: next tile's global loads issue right after the top barrier, hiding under
// QK^T + softmax + PV (registers are dead after COMMIT; WAR with ds_write is compiler-ordered).
__global__ __launch_bounds__(256,4) void attn(
    const bf16* __restrict__ Q, const bf16* __restrict__ Kx,
    const bf16* __restrict__ Vt, bf16* __restrict__ out, int causal)
{
  __shared__ bf16 Ks[64*64];
  __shared__ bf16 Vs[64*64];
  __shared__ bf16 Ps[4][16*64];
  int bid = blockIdx.x;
  int bh = bid & 255;
  int qb = bid >> 8;
  int b = bh >> 3, h = bh & 7;
  int tid = threadIdx.x, wave = tid>>6, lane = tid&63;
  int lhi = lane>>4, llo = lane&15;
  int l7 = llo & 7;
  const bf16* Qb = Q  + (size_t)bh*S_*DH_;
  const bf16* Kb = Kx + (size_t)bh*S_*DH_;
  const bf16* Vb = Vt + (size_t)bh*DH_*S_;

  bf16x8 qf[2];
  #pragma unroll
  for (int f=0; f<2; f++)
    qf[f] = *(const bf16x8*)&Qb[(size_t)(qb*64 + wave*16 + llo)*DH_ + f*32 + lhi*8];

  f32x4 oacc[4];
  #pragma unroll
  for (int f=0; f<4; f++) oacc[f] = (f32x4){0.f,0.f,0.f,0.f};
  float mrow[4], lrow4[4];
  #pragma unroll
  for (int r=0;r<4;r++){ mrow[r] = -1e9f; lrow4[r] = 0.f; }

  int KT = causal ? (qb+1) : (S_/64);

  int srow0 = tid>>3, sslot = tid&7;
  bf16x8 kreg[2], vreg[2];

  auto issue = [&](int kb){
    const bf16* kt0 = Kb + (size_t)kb*64*DH_;
    #pragma unroll
    for (int s=0;s<2;s++){
      int row = s*32 + srow0;
      kreg[s] = *(const bf16x8*)&kt0[(size_t)row*64 + sslot*8];
      vreg[s] = *(const bf16x8*)&Vb[(size_t)row*S_ + (size_t)kb*64 + sslot*8];
    }
  };
  issue(0);

  for (int kb=0; kb<KT; kb++){
    #pragma unroll
    for (int s=0;s<2;s++){
      int row = s*32 + srow0;
      int sl = sslot ^ (row&7);
      *(bf16x8*)&Ks[row*64 + sl*8] = kreg[s];
      *(bf16x8*)&Vs[row*64 + sl*8] = vreg[s];
    }
    __syncthreads();

    // issue next tile immediately: full-iteration latency hiding (regs dead after COMMIT)
    if (kb+1 < KT) issue(kb+1);

    f32x4 sc[4];
    #pragma unroll
    for (int f=0; f<4; f++){
      f32x4 z = (f32x4){0.f,0.f,0.f,0.f};
      #pragma unroll
      for (int ks=0; ks<2; ks++){
        int row = f*16 + llo;
        int slot = (ks*4 + lhi) ^ (row&7);
        bf16x8 kf = *(const bf16x8*)&Ks[row*64 + slot*8];
        z = __builtin_amdgcn_mfma_f32_16x16x32_bf16(qf[ks], kf, z, 0,0,0);
      }
      sc[f] = z;
    }
    #pragma unroll
    for (int f=0; f<4; f++)
      #pragma unroll
      for (int r=0;r<4;r++){
        float v = sc[f][r]*0.125f;
        if (causal && kb==KT-1){
          int gcol = kb*64 + f*16 + llo;
          int grow = qb*64 + wave*16 + lhi*4 + r;
          if (gcol > grow) v = -1e9f;
        }
        sc[f][r] = v;
      }

    float alpha[4], psum[4];
    #pragma unroll
    for (int r=0;r<4;r++){
      float vm = fmaxf(fmaxf(sc[0][r],sc[1][r]), fmaxf(sc[2][r],sc[3][r]));
      #pragma unroll
      for (int msk=1; msk<16; msk<<=1) vm = fmaxf(vm, __shfl_xor(vm, msk));
      float mn = fmaxf(mrow[r], vm);
      alpha[r] = __expf(mrow[r]-mn);
      mrow[r]  = mn;
      psum[r]  = 0.f;
    }
    #pragma unroll
    for (int f=0; f<4; f++)
      #pragma unroll
      for (int r=0;r<4;r++){
        float p = __expf(sc[f][r]-mrow[r]);
        psum[r] += p;
        int row = lhi*4 + r;
        int slot = (f*2 + (llo>>3)) ^ (row&7);
        Ps[wave][row*64 + slot*8 + l7] = (bf16)p;
      }
    #pragma unroll
    for (int r=0;r<4;r++){
      float s = psum[r];
      #pragma unroll
      for (int msk=1; msk<16; msk<<=1) s += __shfl_xor(s, msk);
      lrow4[r] = lrow4[r]*alpha[r] + s;
      #pragma unroll
      for (int f=0; f<4; f++) oacc[f][r] *= alpha[r];
    }

    asm volatile("s_waitcnt lgkmcnt(0)" ::: "memory");
    __builtin_amdgcn_sched_barrier(0);

    #pragma unroll
    for (int ks=0; ks<2; ks++){
      int pslot = (ks*4 + lhi) ^ l7;
      bf16x8 pf = *(const bf16x8*)&Ps[wave][llo*64 + pslot*8];
      #pragma unroll
      for (int f2=0; f2<4; f2++){
        int row = f2*16 + llo;
        int slot = (ks*4 + lhi) ^ (row&7);
        bf16x8 vf = *(const bf16x8*)&Vs[row*64 + slot*8];
        oacc[f2] = __builtin_amdgcn_mfma_f32_16x16x32_bf16(pf, vf, oacc[f2], 0,0,0);
      }
    }
    __syncthreads();
  }

  int qg = qb*64 + wave*16;
  #pragma unroll
  for (int f2=0; f2<4; f2++)
    #pragma unroll
    for (int r=0;r<4;r++){
      int row = qg + lhi*4 + r;
      int dd  = f2*16 + llo;
      out[((size_t)(b*S_ + row))*D_ + h*DH_ + dd] = (bf16)(oacc[f2][r] / lrow4[r]);
    }
}

// ------------------------------------------------------------------
extern "C" void kernel_launch(void* const* d_in, const int* in_sizes, int n_in,
                              void* d_out, int out_size, void* d_ws, size_t ws_size,
                              hipStream_t stream)
{
  (void)in_sizes; (void)n_in; (void)out_size; (void)ws_size;
  const float* enc = (const float*)d_in[0];
  const float* x2  = (const float*)d_in[1];
  const float* bq1 = (const float*)d_in[3];
  const float* bk1 = (const float*)d_in[5];
  const float* bv1 = (const float*)d_in[7];
  const float* bo1 = (const float*)d_in[9];
  const float* bq2 = (const float*)d_in[11];
  const float* bk2 = (const float*)d_in[13];
  const float* bv2 = (const float*)d_in[15];
  const float* bo2 = (const float*)d_in[17];
  float* outp = (float*)d_out;

  char* ws = (char*)d_ws;
  size_t off = 0;
  auto alloc = [&](size_t bytes)->void*{ void* p = ws + off; off += (bytes+255)&~(size_t)255; return p; };
  bf16* Wt8   = (bf16*)alloc((size_t)8*512*512*2);
  bf16* Wff1t = (bf16*)alloc((size_t)DFF_*D_*2);
  bf16* Wff2t = (bf16*)alloc((size_t)D_*DFF_*2);
  float* bnsc = (float*)alloc(4*512*4);
  float* bnsh = (float*)alloc(4*512*4);
  size_t actB = (size_t)NTOK*D_*2;
  bf16* X2b  = (bf16*)alloc(actB);
  bf16* Abuf = (bf16*)alloc(actB);
  bf16* Bbuf = (bf16*)alloc(actB);
  bf16* Cbuf = (bf16*)alloc(actB);
  bf16* Dv   = (bf16*)alloc(actB);
  bf16* E1   = (bf16*)alloc(actB);
  bf16* E2   = (bf16*)alloc(actB);
  bf16* E3   = E2;                   // cross_out bf16 (E2 dead after q2kv2)
  bf16* Fbuf = Abuf;                 // ff1 [NTOK,DFF] overlays Abuf..Dv

  bf16* Wtq1 = Wt8 + 0*262144;   // [1536,512] = q1|k1|v1
  bf16* Wto1 = Wt8 + 3*262144;
  bf16* Wtq2 = Wt8 + 4*262144;   // [1536,512] = q2|k2|v2
  bf16* Wto2 = Wt8 + 7*262144;

  PrepArgs pa;
  pa.w8[0]=(const float*)d_in[2];  pa.w8[1]=(const float*)d_in[4];
  pa.w8[2]=(const float*)d_in[6];  pa.w8[3]=(const float*)d_in[8];
  pa.w8[4]=(const float*)d_in[10]; pa.w8[5]=(const float*)d_in[12];
  pa.w8[6]=(const float*)d_in[14]; pa.w8[7]=(const float*)d_in[16];
  pa.wff1=(const float*)d_in[18];  pa.wff2=(const float*)d_in[19];
  for (int i=0;i<16;i++) pa.bn[i] = (const float*)d_in[20+i];
  prep_all<<<1032 + 2*(NTOK*D_/4/256), 256, 0, stream>>>(pa, Wt8, Wff1t, Wff2t, bnsc, bnsh,
                                                         enc, x2, E2, X2b);

  auto gemm = [&](const bf16* Am, const bf16* W, const float* bb0,
                  const bf16* residb, const float* sc, const float* sh,
                  bf16* oo0, float* of, bf16* pre, int N, int K, int relu){
    gemm_bt<<<(NTOK/64)*(N/128), 256, 0, stream>>>(Am, W, bb0, residb, sc, sh,
                                                   oo0, of, pre, NTOK, N, K, relu);
  };
  auto gemm2 = [&](const bf16* Am, const bf16* A2, int tnA, const bf16* W,
                   const float* bb0, const float* bb1, const float* bb2,
                   bf16* oo0, bf16* oo1, bf16* vt, int vseg,
                   int N, int K, int relu, int mode){
    gemm_bt2<<<(NTOK/128)*(N/128), 256, 0, stream>>>(Am, A2, tnA, W, bb0, bb1, bb2,
                                                     oo0, oo1, vt, vseg,
                                                     NTOK, N, K, relu, mode);
  };

  // ---- self-attention (causal): fused QKV projection; V written transposed ----
  gemm2(X2b, nullptr, 0, Wtq1, bq1, bk1, bv1, Abuf, Bbuf, Dv, 2, 1536, 512, 0, 1);
  attn<<<(S_/64)*B_*H_, 256, 0, stream>>>(Abuf, Bbuf, Dv, Cbuf, 1);
  // xn = bn1(attn@Wo1 + bo1 + x2) -> E1
  gemm(Cbuf, Wto1, bo1, X2b, bnsc+0, bnsh+0, E1, nullptr, nullptr, 512, 512, 0);

  // ---- cross-attention: merged q2(E1) + k2,v2(E2) in one N=1536 launch ----
  gemm2(E1, E2, 4, Wtq2, bq2, bk2, bv2, Abuf, Bbuf, Dv, 2, 1536, 512, 0, 1);
  attn<<<(S_/64)*B_*H_, 256, 0, stream>>>(Abuf, Bbuf, Dv, Cbuf, 0);
  // cross_out(bf16) -> E3 (pre-bn); x3 = bn3(cross_out) -> E1
  gemm(Cbuf, Wto2, bo2, X2b, bnsc+2*512, bnsh+2*512, E1, nullptr, E3, 512, 512, 0);

  // ---- FFN ----
  gemm2(E1, nullptr, 0, Wff1t, nullptr, nullptr, nullptr, Fbuf, nullptr, nullptr, -1,
        DFF_, 512, 1, 0);
  // out = bn4(ff1@Wff2 + cross_out)
  gemm(Fbuf, Wff2t, nullptr, E3, bnsc+3*512, bnsh+3*512, nullptr, outp, nullptr, 512, DFF_, 0);
}

// Round 16
// 301.317 us; speedup vs baseline: 1.8381x; 1.0089x over previous
//
#include <hip/hip_runtime.h>
#include <cstdint>
#include <cstddef>

typedef __bf16 bf16;
typedef __bf16 bf16x8 __attribute__((ext_vector_type(8)));
typedef __bf16 bf16x4 __attribute__((ext_vector_type(4)));
typedef float  f32x4  __attribute__((ext_vector_type(4)));

#define B_   32
#define S_   384
#define D_   512
#define H_   8
#define DH_  64
#define DFF_ 2048
#define NTOK (B_*S_)

__device__ __forceinline__ void gload16(const void* g, void* l){
  __builtin_amdgcn_global_load_lds((__attribute__((address_space(1))) uint32_t*)(g),
                                   (__attribute__((address_space(3))) uint32_t*)(l), 16, 0, 0);
}

// ---------------- fused prep: 10 weight transposes + bn_prep + both activation conversions ----------
struct PrepArgs { const float* w8[8]; const float* wff1; const float* wff2; const float* bn[16]; };
__global__ __launch_bounds__(256) void prep_all(PrepArgs pa, bf16* Wt8, bf16* Wff1t, bf16* Wff2t,
                                                float* sc, float* sh,
                                                const float* __restrict__ enc,
                                                const float* __restrict__ x2,
                                                bf16* __restrict__ E2, bf16* __restrict__ X2b){
  __shared__ float t[64][65];
  int id = blockIdx.x;
  if (id < 1024){
    const float* src; bf16* dst; int R, C, tr, tc;
    if (id < 512){
      int w = id >> 6, tl = id & 63;
      src = pa.w8[w]; dst = Wt8 + (size_t)w*262144; R = 512; C = 512;
      tr = (tl>>3)*64; tc = (tl&7)*64;
    } else if (id < 768){
      int tl = id - 512;                       // Wff1 [512,2048] -> [2048,512]
      src = pa.wff1; dst = Wff1t; R = 512; C = 2048;
      tr = (tl>>5)*64; tc = (tl&31)*64;
    } else {
      int tl = id - 768;                       // Wff2 [2048,512] -> [512,2048]
      src = pa.wff2; dst = Wff2t; R = 2048; C = 512;
      tr = (tl>>3)*64; tc = (tl&7)*64;
    }
    for (int i=threadIdx.x; i<4096; i+=256){ int r=i>>6, c=i&63; t[r][c] = src[(size_t)(tr+r)*C + tc+c]; }
    __syncthreads();
    for (int i=threadIdx.x; i<4096; i+=256){ int c=i>>6, r=i&63; dst[(size_t)(tc+c)*R + tr+r] = (bf16)t[r][c]; }
  } else if (id < 1032){
    int t2 = id - 1024;
    int i = t2 >> 1, half = t2 & 1;
    int n = half*256 + threadIdx.x;
    float g = pa.bn[i*4+0][n], b = pa.bn[i*4+1][n], m = pa.bn[i*4+2][n], v = pa.bn[i*4+3][n];
    float s = g * rsqrtf(v + 1e-3f);
    sc[i*512+n] = s; sh[i*512+n] = b - m*s;
  } else if (id < 1032 + 6144){                // y = bn2(enc) -> E2, inline scale/shift
    size_t e0 = ((size_t)(id-1032)*256 + threadIdx.x)*4;
    int n0 = (int)(e0 & (D_-1));
    f32x4 xv = *(const f32x4*)(enc + e0);
    bf16x4 ov;
    #pragma unroll
    for (int j=0;j<4;j++){
      float g = pa.bn[4][n0+j], b = pa.bn[5][n0+j], m = pa.bn[6][n0+j], v = pa.bn[7][n0+j];
      float s = g * rsqrtf(v + 1e-3f);
      ov[j] = (bf16)(xv[j]*s + (b - m*s));
    }
    *(bf16x4*)(E2 + e0) = ov;
  } else {                                     // bf16(x2) -> X2b
    size_t e0 = ((size_t)(id-1032-6144)*256 + threadIdx.x)*4;
    f32x4 xv = *(const f32x4*)(x2 + e0);
    bf16x4 ov;
    #pragma unroll
    for (int j=0;j<4;j++) ov[j] = (bf16)xv[j];
    *(bf16x4*)(X2b + e0) = ov;
  }
}

// ---------------- 64x128 GEMM (N=512 shapes: o1,o2,ff2), BK=64, 2-phase dbuf, XOR swizzle ------------
__global__ __launch_bounds__(256,3) void gemm_bt(
    const bf16* __restrict__ A, const bf16* __restrict__ Wt,
    const float* __restrict__ b0,
    const bf16* __restrict__ residb,
    const float* __restrict__ bsc, const float* __restrict__ bsh,
    bf16* __restrict__ o0,
    float* __restrict__ of, bf16* __restrict__ pre,
    int M, int N, int K, int relu)
{
  __shared__ bf16 As[2][64*64];
  __shared__ bf16 Bs[2][128*64];
  int nwg = gridDim.x;
  int cpx = nwg >> 3;
  int bid = blockIdx.x;
  int swz = (bid & 7)*cpx + (bid >> 3);
  int tiles_n = N >> 7;
  int tm = swz / tiles_n, tn = swz - tm*tiles_n;

  int tid = threadIdx.x, wave = tid>>6, lane = tid&63;
  int lhi = lane>>4, llo = lane&15;
  int lrow = lane>>3, lcol = lane&7;
  int wr = wave>>1, wc = wave&1;

  f32x4 acc[2][4];
  #pragma unroll
  for (int i=0;i<2;i++)
    #pragma unroll
    for (int j=0;j<4;j++) acc[i][j] = (f32x4){0.f,0.f,0.f,0.f};

  const bf16* Abase = A  + (size_t)(tm*64)  * K;
  const bf16* Bbase = Wt + (size_t)(tn*128) * K;

  int arow0 = wave*16, brow0 = wave*32;

  auto STAGE = [&](int buf, int kt){
    #pragma unroll
    for (int q=0;q<2;q++){
      int r = arow0 + q*8 + lrow;
      int s = lcol ^ (r&7);
      gload16(Abase + (size_t)r*K + kt + s*8, (char*)&As[buf][0] + wave*2048 + q*1024);
    }
    #pragma unroll
    for (int q=0;q<4;q++){
      int r = brow0 + q*8 + lrow;
      int s = lcol ^ (r&7);
      gload16(Bbase + (size_t)r*K + kt + s*8, (char*)&Bs[buf][0] + wave*4096 + q*1024);
    }
  };

  STAGE(0, 0);
  __syncthreads();
  int nt = K >> 6;
  int cur = 0;
  for (int t=0; t<nt; ++t){
    if (t+1 < nt) STAGE(cur^1, (t+1)<<6);
    #pragma unroll
    for (int ks=0; ks<2; ks++){
      bf16x8 af[2], bfr[4];
      #pragma unroll
      for (int i=0;i<2;i++){
        int row = wr*32 + i*16 + llo;
        int slot = (ks*4 + lhi) ^ (row&7);
        af[i] = *(const bf16x8*)&As[cur][row*64 + slot*8];
      }
      #pragma unroll
      for (int j=0;j<4;j++){
        int row = wc*64 + j*16 + llo;
        int slot = (ks*4 + lhi) ^ (row&7);
        bfr[j] = *(const bf16x8*)&Bs[cur][row*64 + slot*8];
      }
      #pragma unroll
      for (int i=0;i<2;i++)
        #pragma unroll
        for (int j=0;j<4;j++)
          acc[i][j] = __builtin_amdgcn_mfma_f32_16x16x32_bf16(af[i], bfr[j], acc[i][j], 0,0,0);
    }
    __syncthreads();
    cur ^= 1;
  }

  int m0 = tm*64 + wr*32, n0 = tn*128 + wc*64;
  #pragma unroll
  for (int i=0;i<2;i++){
    #pragma unroll
    for (int j=0;j<4;j++){
      int gn = n0 + j*16 + llo;
      #pragma unroll
      for (int rr=0;rr<4;rr++){
        int gm = m0 + i*16 + lhi*4 + rr;
        float v = acc[i][j][rr];
        if (b0) v += b0[gn & 511];
        if (residb) v += (float)residb[(size_t)gm*N + gn];
        if (pre)  pre[(size_t)gm*N + gn] = (bf16)v;
        if (bsc)  v = v*bsc[gn & 511] + bsh[gn & 511];
        if (relu) v = fmaxf(v, 0.f);
        if (of) of[(size_t)gm*N + gn] = v;
        else    o0[(size_t)gm*N + gn] = (bf16)v;
      }
    }
  }
}

// ---------------- 128x128 GEMM (big shapes: QKV, q2kv2, ff1), BK=32, 2-phase dbuf ----------------
__global__ __launch_bounds__(256,4) void gemm_bt2(
    const bf16* __restrict__ A, const bf16* __restrict__ A2, int tnA,
    const bf16* __restrict__ Wt,
    const float* __restrict__ b0, const float* __restrict__ b1, const float* __restrict__ b2,
    bf16* __restrict__ o0, bf16* __restrict__ o1b,
    bf16* __restrict__ vt, int vseg,
    int M, int N, int K, int relu, int mode)
{
  __shared__ bf16 As[2][128*32];
  __shared__ bf16 Bs[2][128*32];
  int nwg = gridDim.x;
  int cpx = nwg >> 3;
  int bid = blockIdx.x;
  int swz = (bid & 7)*cpx + (bid >> 3);
  int tiles_n = N >> 7;
  int tm = swz / tiles_n, tn = swz - tm*tiles_n;

  int tid = threadIdx.x, wave = tid>>6, lane = tid&63;
  int lhi = lane>>4, llo = lane&15;
  int srow = lane>>2, sslot = lane&3;
  int wr = wave>>1, wc = wave&1;

  f32x4 acc[4][4];
  #pragma unroll
  for (int i=0;i<4;i++)
    #pragma unroll
    for (int j=0;j<4;j++) acc[i][j] = (f32x4){0.f,0.f,0.f,0.f};

  const bf16* Asrc = (A2 && tn >= tnA) ? A2 : A;
  const bf16* Abase = Asrc + (size_t)(tm*128) * K;
  const bf16* Bbase = Wt   + (size_t)(tn*128) * K;

  auto STAGE = [&](int buf, int kt){
    #pragma unroll
    for (int q=0;q<2;q++){
      int r = wave*32 + q*16 + srow;
      int s = sslot ^ ((r>>1)&3);
      gload16(Abase + (size_t)r*K + kt + s*8, (char*)&As[buf][0] + wave*2048 + q*1024);
    }
    #pragma unroll
    for (int q=0;q<2;q++){
      int r = wave*32 + q*16 + srow;
      int s = sslot ^ ((r>>1)&3);
      gload16(Bbase + (size_t)r*K + kt + s*8, (char*)&Bs[buf][0] + wave*2048 + q*1024);
    }
  };

  STAGE(0, 0);
  __syncthreads();
  int nt = K >> 5;
  int cur = 0;
  for (int t=0; t<nt; ++t){
    if (t+1 < nt) STAGE(cur^1, (t+1)<<5);
    bf16x8 af[4], bfr[4];
    #pragma unroll
    for (int i=0;i<4;i++){
      int row = wr*64 + i*16 + llo;
      int slot = lhi ^ ((row>>1)&3);
      af[i] = *(const bf16x8*)&As[cur][row*32 + slot*8];
    }
    #pragma unroll
    for (int j=0;j<4;j++){
      int row = wc*64 + j*16 + llo;
      int slot = lhi ^ ((row>>1)&3);
      bfr[j] = *(const bf16x8*)&Bs[cur][row*32 + slot*8];
    }
    #pragma unroll
    for (int i=0;i<4;i++)
      #pragma unroll
      for (int j=0;j<4;j++)
        acc[i][j] = __builtin_amdgcn_mfma_f32_16x16x32_bf16(af[i], bfr[j], acc[i][j], 0,0,0);
    __syncthreads();
    cur ^= 1;
  }

  int m0 = tm*128 + wr*64, n0 = tn*128 + wc*64;
  #pragma unroll
  for (int i=0;i<4;i++){
    #pragma unroll
    for (int j=0;j<4;j++){
      int gn = n0 + j*16 + llo;
      float vv[4];
      #pragma unroll
      for (int rr=0;rr<4;rr++){
        int gm = m0 + i*16 + lhi*4 + rr;
        float v = acc[i][j][rr];
        if (b0){
          const float* bp = (gn < 512) ? b0 : ((gn < 1024) ? b1 : b2);
          v += bp[gn & 511];
        }
        vv[rr] = v;
      }
      int gm0 = m0 + i*16 + lhi*4;
      if (mode == 1){
        int seg = gn >> 9, cn = gn & 511;
        int h = cn >> 6, dd = cn & 63;
        int bb = gm0 / S_, ss0 = gm0 - bb*S_;
        if (seg == vseg){
          bf16x4 v4;
          #pragma unroll
          for (int rr=0;rr<4;rr++) v4[rr] = (bf16)vv[rr];
          *(bf16x4*)&vt[((size_t)(bb*H_ + h)*DH_ + dd)*S_ + ss0] = v4;
        } else {
          bf16* hp = (seg == 0) ? o0 : o1b;
          #pragma unroll
          for (int rr=0;rr<4;rr++)
            hp[(((size_t)(bb*H_ + h))*S_ + ss0 + rr)*DH_ + dd] = (bf16)vv[rr];
        }
      } else {
        #pragma unroll
        for (int rr=0;rr<4;rr++){
          int gm = gm0 + rr;
          float v = vv[rr];
          if (relu) v = fmaxf(v, 0.f);
          o0[(size_t)gm*N + gn] = (bf16)v;
        }
      }
    }
  }
}

// ---------------- flash attention: XOR-swizzled LDS, wave-private Ps, XCD-affinity map.
// Heavy-first qb ordering for the causal variant: the 6-tile blocks dispatch first (full
// co-residency); the tail is 1-tile blocks. Bijective; preserves bh%8 == bid%8 XCD affinity.
__global__ __launch_bounds__(256,4) void attn(
    const bf16* __restrict__ Q, const bf16* __restrict__ Kx,
    const bf16* __restrict__ Vt, bf16* __restrict__ out, int causal)
{
  __shared__ bf16 Ks[64*64];
  __shared__ bf16 Vs[64*64];
  __shared__ bf16 Ps[4][16*64];
  int bid = blockIdx.x;
  int bh = bid & 255;
  int qb = (S_/64 - 1) - (bid >> 8);     // heavy-first (qb=5 dispatches first)
  int b = bh >> 3, h = bh & 7;
  int tid = threadIdx.x, wave = tid>>6, lane = tid&63;
  int lhi = lane>>4, llo = lane&15;
  int l7 = llo & 7;
  const bf16* Qb = Q  + (size_t)bh*S_*DH_;
  const bf16* Kb = Kx + (size_t)bh*S_*DH_;
  const bf16* Vb = Vt + (size_t)bh*DH_*S_;

  bf16x8 qf[2];
  #pragma unroll
  for (int f=0; f<2; f++)
    qf[f] = *(const bf16x8*)&Qb[(size_t)(qb*64 + wave*16 + llo)*DH_ + f*32 + lhi*8];

  f32x4 oacc[4];
  #pragma unroll
  for (int f=0; f<4; f++) oacc[f] = (f32x4){0.f,0.f,0.f,0.f};
  float mrow[4], lrow4[4];
  #pragma unroll
  for (int r=0;r<4;r++){ mrow[r] = -1e9f; lrow4[r] = 0.f; }

  int KT = causal ? (qb+1) : (S_/64);

  int srow0 = tid>>3, sslot = tid&7;
  bf16x8 kreg[2], vreg[2];

  auto issue = [&](int kb){
    const bf16* kt0 = Kb + (size_t)kb*64*DH_;
    #pragma unroll
    for (int s=0;s<2;s++){
      int row = s*32 + srow0;
      kreg[s] = *(const bf16x8*)&kt0[(size_t)row*64 + sslot*8];
      vreg[s] = *(const bf16x8*)&Vb[(size_t)row*S_ + (size_t)kb*64 + sslot*8];
    }
  };
  issue(0);

  for (int kb=0; kb<KT; kb++){
    #pragma unroll
    for (int s=0;s<2;s++){
      int row = s*32 + srow0;
      int sl = sslot ^ (row&7);
      *(bf16x8*)&Ks[row*64 + sl*8] = kreg[s];
      *(bf16x8*)&Vs[row*64 + sl*8] = vreg[s];
    }
    __syncthreads();

    if (kb+1 < KT) issue(kb+1);

    f32x4 sc[4];
    #pragma unroll
    for (int f=0; f<4; f++){
      f32x4 z = (f32x4){0.f,0.f,0.f,0.f};
      #pragma unroll
      for (int ks=0; ks<2; ks++){
        int row = f*16 + llo;
        int slot = (ks*4 + lhi) ^ (row&7);
        bf16x8 kf = *(const bf16x8*)&Ks[row*64 + slot*8];
        z = __builtin_amdgcn_mfma_f32_16x16x32_bf16(qf[ks], kf, z, 0,0,0);
      }
      sc[f] = z;
    }
    #pragma unroll
    for (int f=0; f<4; f++)
      #pragma unroll
      for (int r=0;r<4;r++){
        float v = sc[f][r]*0.125f;
        if (causal && kb==KT-1){
          int gcol = kb*64 + f*16 + llo;
          int grow = qb*64 + wave*16 + lhi*4 + r;
          if (gcol > grow) v = -1e9f;
        }
        sc[f][r] = v;
      }

    float alpha[4], psum[4];
    #pragma unroll
    for (int r=0;r<4;r++){
      float vm = fmaxf(fmaxf(sc[0][r],sc[1][r]), fmaxf(sc[2][r],sc[3][r]));
      #pragma unroll
      for (int msk=1; msk<16; msk<<=1) vm = fmaxf(vm, __shfl_xor(vm, msk));
      float mn = fmaxf(mrow[r], vm);
      alpha[r] = __expf(mrow[r]-mn);
      mrow[r]  = mn;
      psum[r]  = 0.f;
    }
    #pragma unroll
    for (int f=0; f<4; f++)
      #pragma unroll
      for (int r=0;r<4;r++){
        float p = __expf(sc[f][r]-mrow[r]);
        psum[r] += p;
        int row = lhi*4 + r;
        int slot = (f*2 + (llo>>3)) ^ (row&7);
        Ps[wave][row*64 + slot*8 + l7] = (bf16)p;
      }
    #pragma unroll
    for (int r=0;r<4;r++){
      float s = psum[r];
      #pragma unroll
      for (int msk=1; msk<16; msk<<=1) s += __shfl_xor(s, msk);
      lrow4[r] = lrow4[r]*alpha[r] + s;
      #pragma unroll
      for (int f=0; f<4; f++) oacc[f][r] *= alpha[r];
    }

    asm volatile("s_waitcnt lgkmcnt(0)" ::: "memory");
    __builtin_amdgcn_sched_barrier(0);

    #pragma unroll
    for (int ks=0; ks<2; ks++){
      int pslot = (ks*4 + lhi) ^ l7;
      bf16x8 pf = *(const bf16x8*)&Ps[wave][llo*64 + pslot*8];
      #pragma unroll
      for (int f2=0; f2<4; f2++){
        int row = f2*16 + llo;
        int slot = (ks*4 + lhi) ^ (row&7);
        bf16x8 vf = *(const bf16x8*)&Vs[row*64 + slot*8];
        oacc[f2] = __builtin_amdgcn_mfma_f32_16x16x32_bf16(pf, vf, oacc[f2], 0,0,0);
      }
    }
    __syncthreads();
  }

  float invl[4];
  #pragma unroll
  for (int r=0;r<4;r++) invl[r] = 1.0f / lrow4[r];
  int qg = qb*64 + wave*16;
  #pragma unroll
  for (int f2=0; f2<4; f2++)
    #pragma unroll
    for (int r=0;r<4;r++){
      int row = qg + lhi*4 + r;
      int dd  = f2*16 + llo;
      out[((size_t)(b*S_ + row))*D_ + h*DH_ + dd] = (bf16)(oacc[f2][r] * invl[r]);
    }
}

// ------------------------------------------------------------------
extern "C" void kernel_launch(void* const* d_in, const int* in_sizes, int n_in,
                              void* d_out, int out_size, void* d_ws, size_t ws_size,
                              hipStream_t stream)
{
  (void)in_sizes; (void)n_in; (void)out_size; (void)ws_size;
  const float* enc = (const float*)d_in[0];
  const float* x2  = (const float*)d_in[1];
  const float* bq1 = (const float*)d_in[3];
  const float* bk1 = (const float*)d_in[5];
  const float* bv1 = (const float*)d_in[7];
  const float* bo1 = (const float*)d_in[9];
  const float* bq2 = (const float*)d_in[11];
  const float* bk2 = (const float*)d_in[13];
  const float* bv2 = (const float*)d_in[15];
  const float* bo2 = (const float*)d_in[17];
  float* outp = (float*)d_out;

  char* ws = (char*)d_ws;
  size_t off = 0;
  auto alloc = [&](size_t bytes)->void*{ void* p = ws + off; off += (bytes+255)&~(size_t)255; return p; };
  bf16* Wt8   = (bf16*)alloc((size_t)8*512*512*2);
  bf16* Wff1t = (bf16*)alloc((size_t)DFF_*D_*2);
  bf16* Wff2t = (bf16*)alloc((size_t)D_*DFF_*2);
  float* bnsc = (float*)alloc(4*512*4);
  float* bnsh = (float*)alloc(4*512*4);
  size_t actB = (size_t)NTOK*D_*2;
  bf16* X2b  = (bf16*)alloc(actB);
  bf16* Abuf = (bf16*)alloc(actB);
  bf16* Bbuf = (bf16*)alloc(actB);
  bf16* Cbuf = (bf16*)alloc(actB);
  bf16* Dv   = (bf16*)alloc(actB);
  bf16* E1   = (bf16*)alloc(actB);
  bf16* E2   = (bf16*)alloc(actB);
  bf16* E3   = E2;                   // cross_out bf16 (E2 dead after q2kv2)
  bf16* Fbuf = Abuf;                 // ff1 [NTOK,DFF] overlays Abuf..Dv

  bf16* Wtq1 = Wt8 + 0*262144;   // [1536,512] = q1|k1|v1
  bf16* Wto1 = Wt8 + 3*262144;
  bf16* Wtq2 = Wt8 + 4*262144;   // [1536,512] = q2|k2|v2
  bf16* Wto2 = Wt8 + 7*262144;

  PrepArgs pa;
  pa.w8[0]=(const float*)d_in[2];  pa.w8[1]=(const float*)d_in[4];
  pa.w8[2]=(const float*)d_in[6];  pa.w8[3]=(const float*)d_in[8];
  pa.w8[4]=(const float*)d_in[10]; pa.w8[5]=(const float*)d_in[12];
  pa.w8[6]=(const float*)d_in[14]; pa.w8[7]=(const float*)d_in[16];
  pa.wff1=(const float*)d_in[18];  pa.wff2=(const float*)d_in[19];
  for (int i=0;i<16;i++) pa.bn[i] = (const float*)d_in[20+i];
  prep_all<<<1032 + 2*(NTOK*D_/4/256), 256, 0, stream>>>(pa, Wt8, Wff1t, Wff2t, bnsc, bnsh,
                                                         enc, x2, E2, X2b);

  auto gemm = [&](const bf16* Am, const bf16* W, const float* bb0,
                  const bf16* residb, const float* sc, const float* sh,
                  bf16* oo0, float* of, bf16* pre, int N, int K, int relu){
    gemm_bt<<<(NTOK/64)*(N/128), 256, 0, stream>>>(Am, W, bb0, residb, sc, sh,
                                                   oo0, of, pre, NTOK, N, K, relu);
  };
  auto gemm2 = [&](const bf16* Am, const bf16* A2, int tnA, const bf16* W,
                   const float* bb0, const float* bb1, const float* bb2,
                   bf16* oo0, bf16* oo1, bf16* vt, int vseg,
                   int N, int K, int relu, int mode){
    gemm_bt2<<<(NTOK/128)*(N/128), 256, 0, stream>>>(Am, A2, tnA, W, bb0, bb1, bb2,
                                                     oo0, oo1, vt, vseg,
                                                     NTOK, N, K, relu, mode);
  };

  // ---- self-attention (causal): fused QKV projection; V written transposed ----
  gemm2(X2b, nullptr, 0, Wtq1, bq1, bk1, bv1, Abuf, Bbuf, Dv, 2, 1536, 512, 0, 1);
  attn<<<(S_/64)*B_*H_, 256, 0, stream>>>(Abuf, Bbuf, Dv, Cbuf, 1);
  // xn = bn1(attn@Wo1 + bo1 + x2) -> E1
  gemm(Cbuf, Wto1, bo1, X2b, bnsc+0, bnsh+0, E1, nullptr, nullptr, 512, 512, 0);

  // ---- cross-attention: merged q2(E1) + k2,v2(E2) in one N=1536 launch ----
  gemm2(E1, E2, 4, Wtq2, bq2, bk2, bv2, Abuf, Bbuf, Dv, 2, 1536, 512, 0, 1);
  attn<<<(S_/64)*B_*H_, 256, 0, stream>>>(Abuf, Bbuf, Dv, Cbuf, 0);
  // cross_out(bf16) -> E3 (pre-bn); x3 = bn3(cross_out) -> E1
  gemm(Cbuf, Wto2, bo2, X2b, bnsc+2*512, bnsh+2*512, E1, nullptr, E3, 512, 512, 0);

  // ---- FFN ----
  gemm2(E1, nullptr, 0, Wff1t, nullptr, nullptr, nullptr, Fbuf, nullptr, nullptr, -1,
        DFF_, 512, 1, 0);
  // out = bn4(ff1@Wff2 + cross_out)
  gemm(Fbuf, Wff2t, nullptr, E3, bnsc+3*512, bnsh+3*512, nullptr, outp, nullptr, 512, DFF_, 0);
}